// Round 1
// baseline (1483.025 us; speedup 1.0000x reference)
//
#include <hip/hip_runtime.h>
#include <math.h>

#define NN 100000
#define EE 800000
// HID=64, HEADS=4, OBS=128, ACT=32

// ---------------- GEMM: C[M,Nc] = A[M,K] @ B[K,Nc] (+bias, optional relu) ----------------
__global__ __launch_bounds__(256) void gemm_kernel(
    const float* __restrict__ A, const float* __restrict__ B,
    const float* __restrict__ bias, float* __restrict__ C,
    int M, int K, int Nc, int doRelu)
{
    __shared__ float sA[16][65];   // [k][row]  (+pad to dodge write conflicts)
    __shared__ float sB[16][65];   // [k][col]

    const int bm = blockIdx.x * 64;
    const int bn = blockIdx.y * 64;
    const int tid = threadIdx.x;
    const int tx = tid & 15;       // col group (4 cols each)
    const int ty = tid >> 4;       // row group (4 rows each)

    float acc[4][4] = {};

    for (int k0 = 0; k0 < K; k0 += 16) {
        // A tile: 64 rows x 16 k   (K is always a multiple of 16 here)
#pragma unroll
        for (int i = 0; i < 4; ++i) {
            int idx = tid + i * 256;
            int r = idx >> 4;          // 0..63
            int c = idx & 15;          // 0..15
            int gr = bm + r;
            sA[c][r] = (gr < M) ? A[(size_t)gr * K + k0 + c] : 0.f;
        }
        // B tile: 16 k x 64 cols
#pragma unroll
        for (int i = 0; i < 4; ++i) {
            int idx = tid + i * 256;
            int r = idx >> 6;          // 0..15
            int c = idx & 63;          // 0..63
            int gc = bn + c;
            sB[r][c] = (gc < Nc) ? B[(size_t)(k0 + r) * Nc + gc] : 0.f;
        }
        __syncthreads();
#pragma unroll
        for (int k = 0; k < 16; ++k) {
            float a[4], b[4];
#pragma unroll
            for (int i = 0; i < 4; ++i) a[i] = sA[k][ty * 4 + i];
#pragma unroll
            for (int j = 0; j < 4; ++j) b[j] = sB[k][tx * 4 + j];
#pragma unroll
            for (int i = 0; i < 4; ++i)
#pragma unroll
                for (int j = 0; j < 4; ++j) acc[i][j] += a[i] * b[j];
        }
        __syncthreads();
    }

#pragma unroll
    for (int i = 0; i < 4; ++i) {
        int gr = bm + ty * 4 + i;
        if (gr >= M) continue;
#pragma unroll
        for (int j = 0; j < 4; ++j) {
            int gc = bn + tx * 4 + j;
            if (gc >= Nc) continue;
            float v = acc[i][j] + (bias ? bias[gc] : 0.f);
            if (doRelu) v = fmaxf(v, 0.f);
            C[(size_t)gr * Nc + gc] = v;
        }
    }
}

// ---------------- attention scores: a_src[n,h] = sum_d xl[n,h,d]*att_src[h,d] ----------------
__global__ __launch_bounds__(256) void att_scores_kernel(
    const float* __restrict__ xl, const float* __restrict__ att_src,
    const float* __restrict__ att_dst, float* __restrict__ a_src,
    float* __restrict__ a_dst, int Nn)
{
    __shared__ float s_src[256], s_dst[256];
    int tid = threadIdx.x;
    s_src[tid] = att_src[tid];
    s_dst[tid] = att_dst[tid];
    __syncthreads();

    int gid = blockIdx.x * 256 + tid;
    if (gid >= Nn * 4) return;
    int n = gid >> 2, h = gid & 3;

    const float4* xp  = (const float4*)(xl + (size_t)n * 256 + h * 64);
    const float4* ap  = (const float4*)(s_src + h * 64);
    const float4* bp  = (const float4*)(s_dst + h * 64);
    float ss = 0.f, sd = 0.f;
#pragma unroll
    for (int i = 0; i < 16; ++i) {
        float4 v = xp[i], a = ap[i], b = bp[i];
        ss += v.x * a.x + v.y * a.y + v.z * a.z + v.w * a.w;
        sd += v.x * b.x + v.y * b.y + v.z * b.z + v.w * b.w;
    }
    a_src[gid] = ss;
    a_dst[gid] = sd;
}

// ---------------- order-preserving float<->uint for atomicMax ----------------
__device__ __forceinline__ unsigned enc_f(float f) {
    unsigned u = __float_as_uint(f);
    return (u & 0x80000000u) ? ~u : (u | 0x80000000u);
}
__device__ __forceinline__ float dec_f(unsigned u) {
    return (u & 0x80000000u) ? __uint_as_float(u & 0x7fffffffu) : __uint_as_float(~u);
}

__device__ __forceinline__ float lrelu(float x) { return x > 0.f ? x : 0.2f * x; }

// ---------------- pass 1: segment max ----------------
__global__ __launch_bounds__(256) void edge_max_kernel(
    const int* __restrict__ ei, const float* __restrict__ a_src,
    const float* __restrict__ a_dst, unsigned* __restrict__ m_enc)
{
    int e = blockIdx.x * 256 + threadIdx.x;
    if (e >= EE + NN) return;
    int s_, d_;
    if (e < EE) { s_ = ei[e]; d_ = ei[EE + e]; }
    else        { s_ = d_ = e - EE; }
#pragma unroll
    for (int h = 0; h < 4; ++h) {
        float al = lrelu(a_src[s_ * 4 + h] + a_dst[d_ * 4 + h]);
        atomicMax(&m_enc[d_ * 4 + h], enc_f(al));
    }
}

__global__ __launch_bounds__(256) void decode_max_kernel(unsigned* __restrict__ m, int n)
{
    int i = blockIdx.x * 256 + threadIdx.x;
    if (i < n) ((float*)m)[i] = dec_f(m[i]);
}

// ---------------- pass 2: segment sum of exp ----------------
__global__ __launch_bounds__(256) void edge_expsum_kernel(
    const int* __restrict__ ei, const float* __restrict__ a_src,
    const float* __restrict__ a_dst, const float* __restrict__ mf,
    float* __restrict__ ssum)
{
    int e = blockIdx.x * 256 + threadIdx.x;
    if (e >= EE + NN) return;
    int s_, d_;
    if (e < EE) { s_ = ei[e]; d_ = ei[EE + e]; }
    else        { s_ = d_ = e - EE; }
#pragma unroll
    for (int h = 0; h < 4; ++h) {
        float al = lrelu(a_src[s_ * 4 + h] + a_dst[d_ * 4 + h]);
        atomicAdd(&ssum[d_ * 4 + h], expf(al - mf[d_ * 4 + h]));
    }
}

// ---------------- pass 3: weighted scatter (wave per edge, lane = feature dim) ----------------
__global__ __launch_bounds__(256) void edge_scatter_kernel(
    const int* __restrict__ ei, const float* __restrict__ a_src,
    const float* __restrict__ a_dst, const float* __restrict__ mf,
    const float* __restrict__ ssum, const float* __restrict__ xl,
    float* __restrict__ acc)
{
    int widx = (blockIdx.x * 256 + threadIdx.x) >> 6;  // one wave (64 lanes) per edge
    int lane = threadIdx.x & 63;
    if (widx >= EE + NN) return;
    int s_, d_;
    if (widx < EE) { s_ = ei[widx]; d_ = ei[EE + widx]; }
    else           { s_ = d_ = widx - EE; }

    float w[4];
#pragma unroll
    for (int h = 0; h < 4; ++h) {
        float al = lrelu(a_src[s_ * 4 + h] + a_dst[d_ * 4 + h]);
        w[h] = expf(al - mf[d_ * 4 + h]) / ssum[d_ * 4 + h] * 0.25f;  // 0.25 = head mean
    }
    const float* xp = xl + (size_t)s_ * 256;
    float v = xp[lane] * w[0] + xp[64 + lane] * w[1] + xp[128 + lane] * w[2] + xp[192 + lane] * w[3];
    atomicAdd(&acc[(size_t)d_ * 64 + lane], v);
}

// ---------------- bias + relu ----------------
__global__ __launch_bounds__(256) void bias_relu_kernel(
    const float* __restrict__ acc, const float* __restrict__ b,
    float* __restrict__ out, int total)
{
    int i = blockIdx.x * 256 + threadIdx.x;
    if (i < total) out[i] = fmaxf(acc[i] + b[i & 63], 0.f);
}

// ---------------- host-side GAT layer ----------------
static void gat_layer(const float* x, const float* W, const float* attS, const float* attD,
                      const float* b, const int* ei,
                      float* xl, float* a_src, float* a_dst, unsigned* m, float* ssum,
                      float* acc, float* xout, hipStream_t stream)
{
    // xl = x @ W  [N,64]@[64,256]
    gemm_kernel<<<dim3((NN + 63) / 64, 4), 256, 0, stream>>>(x, W, nullptr, xl, NN, 64, 256, 0);
    att_scores_kernel<<<(NN * 4 + 255) / 256, 256, 0, stream>>>(xl, attS, attD, a_src, a_dst, NN);

    hipMemsetAsync(m, 0, (size_t)NN * 4 * sizeof(unsigned), stream);
    hipMemsetAsync(ssum, 0, (size_t)NN * 4 * sizeof(float), stream);
    hipMemsetAsync(acc, 0, (size_t)NN * 64 * sizeof(float), stream);

    int Etot = EE + NN;
    edge_max_kernel<<<(Etot + 255) / 256, 256, 0, stream>>>(ei, a_src, a_dst, m);
    decode_max_kernel<<<(NN * 4 + 255) / 256, 256, 0, stream>>>(m, NN * 4);
    edge_expsum_kernel<<<(Etot + 255) / 256, 256, 0, stream>>>(ei, a_src, a_dst, (const float*)m, ssum);
    edge_scatter_kernel<<<((size_t)Etot * 64 + 255) / 256, 256, 0, stream>>>(
        ei, a_src, a_dst, (const float*)m, ssum, xl, acc);
    bias_relu_kernel<<<(NN * 64 + 255) / 256, 256, 0, stream>>>(acc, b, xout, NN * 64);
}

extern "C" void kernel_launch(void* const* d_in, const int* in_sizes, int n_in,
                              void* d_out, int out_size, void* d_ws, size_t ws_size,
                              hipStream_t stream)
{
    const float* obs     = (const float*)d_in[0];
    const int*   ei      = (const int*)d_in[1];
    const float* enc_w1  = (const float*)d_in[2];
    const float* enc_b1  = (const float*)d_in[3];
    const float* enc_w2  = (const float*)d_in[4];
    const float* enc_b2  = (const float*)d_in[5];
    const float* gat1_w  = (const float*)d_in[6];
    const float* gat1_as = (const float*)d_in[7];
    const float* gat1_ad = (const float*)d_in[8];
    const float* gat1_b  = (const float*)d_in[9];
    const float* gat2_w  = (const float*)d_in[10];
    const float* gat2_as = (const float*)d_in[11];
    const float* gat2_ad = (const float*)d_in[12];
    const float* gat2_b  = (const float*)d_in[13];
    const float* dec_w1  = (const float*)d_in[14];
    const float* dec_b1  = (const float*)d_in[15];
    const float* dec_w2  = (const float*)d_in[16];
    const float* dec_b2  = (const float*)d_in[17];

    float* ws = (float*)d_ws;
    float* bufA  = ws;                              // [N,64]
    float* bufB  = bufA + (size_t)NN * 64;          // [N,64]
    float* xl    = bufB + (size_t)NN * 64;          // [N,256]
    float* a_src = xl + (size_t)NN * 256;           // [N,4]
    float* a_dst = a_src + (size_t)NN * 4;          // [N,4]
    unsigned* m  = (unsigned*)(a_dst + (size_t)NN * 4); // [N,4]
    float* ssum  = (float*)m + (size_t)NN * 4;      // [N,4]

    // encoder: bufA = relu(obs @ w1 + b1); bufB = bufA @ w2 + b2
    gemm_kernel<<<dim3((NN + 63) / 64, 1), 256, 0, stream>>>(obs, enc_w1, enc_b1, bufA, NN, 128, 64, 1);
    gemm_kernel<<<dim3((NN + 63) / 64, 1), 256, 0, stream>>>(bufA, enc_w2, enc_b2, bufB, NN, 64, 64, 0);

    // GAT layers (in/out: bufB)
    gat_layer(bufB, gat1_w, gat1_as, gat1_ad, gat1_b, ei, xl, a_src, a_dst, m, ssum, bufA, bufB, stream);
    gat_layer(bufB, gat2_w, gat2_as, gat2_ad, gat2_b, ei, xl, a_src, a_dst, m, ssum, bufA, bufB, stream);

    // decoder: bufA = relu(bufB @ dec_w1 + b1); out = bufA @ dec_w2 + b2
    gemm_kernel<<<dim3((NN + 63) / 64, 1), 256, 0, stream>>>(bufB, dec_w1, dec_b1, bufA, NN, 64, 64, 1);
    gemm_kernel<<<dim3((NN + 63) / 64, 1), 256, 0, stream>>>(bufA, dec_w2, dec_b2, (float*)d_out, NN, 64, 32, 0);
}

// Round 2
// 1432.502 us; speedup vs baseline: 1.0353x; 1.0353x over previous
//
#include <hip/hip_runtime.h>
#include <math.h>

#define NN 100000
#define EE 800000
#define ETOT (EE + NN)
// HID=64, HEADS=4, OBS=128, ACT=32

// ---------------- GEMM: C[M,Nc] = A[M,K] @ B[K,Nc] (+bias, optional relu) ----------------
__global__ __launch_bounds__(256) void gemm_kernel(
    const float* __restrict__ A, const float* __restrict__ B,
    const float* __restrict__ bias, float* __restrict__ C,
    int M, int K, int Nc, int doRelu)
{
    __shared__ float sA[16][65];   // [k][row]
    __shared__ float sB[16][65];   // [k][col]

    const int bm = blockIdx.x * 64;
    const int bn = blockIdx.y * 64;
    const int tid = threadIdx.x;
    const int tx = tid & 15;       // col group (4 cols each)
    const int ty = tid >> 4;       // row group (4 rows each)

    float acc[4][4] = {};

    for (int k0 = 0; k0 < K; k0 += 16) {
#pragma unroll
        for (int i = 0; i < 4; ++i) {
            int idx = tid + i * 256;
            int r = idx >> 4;          // 0..63
            int c = idx & 15;          // 0..15
            int gr = bm + r;
            sA[c][r] = (gr < M) ? A[(size_t)gr * K + k0 + c] : 0.f;
        }
#pragma unroll
        for (int i = 0; i < 4; ++i) {
            int idx = tid + i * 256;
            int r = idx >> 6;          // 0..15
            int c = idx & 63;          // 0..63
            int gc = bn + c;
            sB[r][c] = (gc < Nc) ? B[(size_t)(k0 + r) * Nc + gc] : 0.f;
        }
        __syncthreads();
#pragma unroll
        for (int k = 0; k < 16; ++k) {
            float a[4], b[4];
#pragma unroll
            for (int i = 0; i < 4; ++i) a[i] = sA[k][ty * 4 + i];
#pragma unroll
            for (int j = 0; j < 4; ++j) b[j] = sB[k][tx * 4 + j];
#pragma unroll
            for (int i = 0; i < 4; ++i)
#pragma unroll
                for (int j = 0; j < 4; ++j) acc[i][j] += a[i] * b[j];
        }
        __syncthreads();
    }

#pragma unroll
    for (int i = 0; i < 4; ++i) {
        int gr = bm + ty * 4 + i;
        if (gr >= M) continue;
#pragma unroll
        for (int j = 0; j < 4; ++j) {
            int gc = bn + tx * 4 + j;
            if (gc >= Nc) continue;
            float v = acc[i][j] + (bias ? bias[gc] : 0.f);
            if (doRelu) v = fmaxf(v, 0.f);
            C[(size_t)gr * Nc + gc] = v;
        }
    }
}

// ---------------- attention scores ----------------
__global__ __launch_bounds__(256) void att_scores_kernel(
    const float* __restrict__ xl, const float* __restrict__ att_src,
    const float* __restrict__ att_dst, float* __restrict__ a_src,
    float* __restrict__ a_dst, int Nn)
{
    __shared__ float s_src[256], s_dst[256];
    int tid = threadIdx.x;
    s_src[tid] = att_src[tid];
    s_dst[tid] = att_dst[tid];
    __syncthreads();

    int gid = blockIdx.x * 256 + tid;
    if (gid >= Nn * 4) return;
    int n = gid >> 2, h = gid & 3;

    const float4* xp  = (const float4*)(xl + (size_t)n * 256 + h * 64);
    const float4* ap  = (const float4*)(s_src + h * 64);
    const float4* bp  = (const float4*)(s_dst + h * 64);
    float ss = 0.f, sd = 0.f;
#pragma unroll
    for (int i = 0; i < 16; ++i) {
        float4 v = xp[i], a = ap[i], b = bp[i];
        ss += v.x * a.x + v.y * a.y + v.z * a.z + v.w * a.w;
        sd += v.x * b.x + v.y * b.y + v.z * b.z + v.w * b.w;
    }
    a_src[gid] = ss;
    a_dst[gid] = sd;
}

// ---------------- order-preserving float<->uint for atomicMax ----------------
__device__ __forceinline__ unsigned enc_f(float f) {
    unsigned u = __float_as_uint(f);
    return (u & 0x80000000u) ? ~u : (u | 0x80000000u);
}
__device__ __forceinline__ float dec_f(unsigned u) {
    return (u & 0x80000000u) ? __uint_as_float(u & 0x7fffffffu) : __uint_as_float(~u);
}

__device__ __forceinline__ float lrelu(float x) { return x > 0.f ? x : 0.2f * x; }

// ---------------- pass 1: compute alpha (stored) + segment max ----------------
__global__ __launch_bounds__(256) void edge_alpha_max(
    const int* __restrict__ ei, const float* __restrict__ a_src,
    const float* __restrict__ a_dst, float4* __restrict__ alph,
    unsigned* __restrict__ m_enc)
{
    int e = blockIdx.x * 256 + threadIdx.x;
    if (e >= ETOT) return;
    int s_, d_;
    if (e < EE) { s_ = ei[e]; d_ = ei[EE + e]; }
    else        { s_ = d_ = e - EE; }
    float4 as = ((const float4*)a_src)[s_];
    float4 ad = ((const float4*)a_dst)[d_];
    float4 al;
    al.x = lrelu(as.x + ad.x);
    al.y = lrelu(as.y + ad.y);
    al.z = lrelu(as.z + ad.z);
    al.w = lrelu(as.w + ad.w);
    alph[e] = al;
    atomicMax(&m_enc[d_ * 4 + 0], enc_f(al.x));
    atomicMax(&m_enc[d_ * 4 + 1], enc_f(al.y));
    atomicMax(&m_enc[d_ * 4 + 2], enc_f(al.z));
    atomicMax(&m_enc[d_ * 4 + 3], enc_f(al.w));
}

__global__ __launch_bounds__(256) void decode_max_kernel(unsigned* __restrict__ m, int n)
{
    int i = blockIdx.x * 256 + threadIdx.x;
    if (i < n) ((float*)m)[i] = dec_f(m[i]);
}

// ---------------- pass 2: p = exp(alpha-m) (stored in place) + segment sum ----------------
__global__ __launch_bounds__(256) void edge_p_sum(
    const int* __restrict__ ei, const float* __restrict__ mf,
    float4* __restrict__ alph, float* __restrict__ ssum)
{
    int e = blockIdx.x * 256 + threadIdx.x;
    if (e >= ETOT) return;
    int d_ = (e < EE) ? ei[EE + e] : e - EE;
    float4 al = alph[e];
    float4 mv = ((const float4*)mf)[d_];
    float4 p;
    p.x = expf(al.x - mv.x);
    p.y = expf(al.y - mv.y);
    p.z = expf(al.z - mv.z);
    p.w = expf(al.w - mv.w);
    alph[e] = p;
    atomicAdd(&ssum[d_ * 4 + 0], p.x);
    atomicAdd(&ssum[d_ * 4 + 1], p.y);
    atomicAdd(&ssum[d_ * 4 + 2], p.z);
    atomicAdd(&ssum[d_ * 4 + 3], p.w);
}

// ---------------- pass 3: w = p / ssum * 0.25 (stored in place) ----------------
__global__ __launch_bounds__(256) void edge_w_kernel(
    const int* __restrict__ ei, const float* __restrict__ ssum,
    float4* __restrict__ alph)
{
    int e = blockIdx.x * 256 + threadIdx.x;
    if (e >= ETOT) return;
    int d_ = (e < EE) ? ei[EE + e] : e - EE;
    float4 p = alph[e];
    float4 sv = ((const float4*)ssum)[d_];
    p.x = p.x / sv.x * 0.25f;
    p.y = p.y / sv.y * 0.25f;
    p.z = p.z / sv.z * 0.25f;
    p.w = p.w / sv.w * 0.25f;
    alph[e] = p;
}

// ---------------- pass 4: weighted scatter (wave per edge, lane = feature dim) ----------------
__global__ __launch_bounds__(256) void edge_scatter_kernel(
    const int* __restrict__ ei, const float4* __restrict__ w4,
    const float* __restrict__ xl, float* __restrict__ acc)
{
    int widx = (blockIdx.x * 256 + threadIdx.x) >> 6;  // one wave per edge
    int lane = threadIdx.x & 63;
    if (widx >= ETOT) return;
    int s_, d_;
    if (widx < EE) { s_ = ei[widx]; d_ = ei[EE + widx]; }
    else           { s_ = d_ = widx - EE; }
    float4 w = w4[widx];  // same address across wave -> broadcast from cache
    const float* xp = xl + (size_t)s_ * 256;
    float v = xp[lane] * w.x + xp[64 + lane] * w.y + xp[128 + lane] * w.z + xp[192 + lane] * w.w;
    atomicAdd(&acc[(size_t)d_ * 64 + lane], v);
}

// ---------------- bias + relu ----------------
__global__ __launch_bounds__(256) void bias_relu_kernel(
    const float* __restrict__ acc, const float* __restrict__ b,
    float* __restrict__ out, int total)
{
    int i = blockIdx.x * 256 + threadIdx.x;
    if (i < total) out[i] = fmaxf(acc[i] + b[i & 63], 0.f);
}

// ---------------- host-side GAT layer ----------------
static void gat_layer(const float* x, const float* W, const float* attS, const float* attD,
                      const float* b, const int* ei,
                      float* xl, float* a_src, float* a_dst, unsigned* m, float* ssum,
                      float4* alph, float* acc, float* xout, hipStream_t stream)
{
    gemm_kernel<<<dim3((NN + 63) / 64, 4), 256, 0, stream>>>(x, W, nullptr, xl, NN, 64, 256, 0);
    att_scores_kernel<<<(NN * 4 + 255) / 256, 256, 0, stream>>>(xl, attS, attD, a_src, a_dst, NN);

    hipMemsetAsync(m, 0, (size_t)NN * 4 * sizeof(unsigned), stream);
    hipMemsetAsync(ssum, 0, (size_t)NN * 4 * sizeof(float), stream);
    hipMemsetAsync(acc, 0, (size_t)NN * 64 * sizeof(float), stream);

    const int EB = (ETOT + 255) / 256;
    edge_alpha_max<<<EB, 256, 0, stream>>>(ei, a_src, a_dst, alph, m);
    decode_max_kernel<<<(NN * 4 + 255) / 256, 256, 0, stream>>>(m, NN * 4);
    edge_p_sum<<<EB, 256, 0, stream>>>(ei, (const float*)m, alph, ssum);
    edge_w_kernel<<<EB, 256, 0, stream>>>(ei, ssum, alph);
    edge_scatter_kernel<<<((size_t)ETOT * 64 + 255) / 256, 256, 0, stream>>>(
        ei, (const float4*)alph, xl, acc);
    bias_relu_kernel<<<(NN * 64 + 255) / 256, 256, 0, stream>>>(acc, b, xout, NN * 64);
}

extern "C" void kernel_launch(void* const* d_in, const int* in_sizes, int n_in,
                              void* d_out, int out_size, void* d_ws, size_t ws_size,
                              hipStream_t stream)
{
    const float* obs     = (const float*)d_in[0];
    const int*   ei      = (const int*)d_in[1];
    const float* enc_w1  = (const float*)d_in[2];
    const float* enc_b1  = (const float*)d_in[3];
    const float* enc_w2  = (const float*)d_in[4];
    const float* enc_b2  = (const float*)d_in[5];
    const float* gat1_w  = (const float*)d_in[6];
    const float* gat1_as = (const float*)d_in[7];
    const float* gat1_ad = (const float*)d_in[8];
    const float* gat1_b  = (const float*)d_in[9];
    const float* gat2_w  = (const float*)d_in[10];
    const float* gat2_as = (const float*)d_in[11];
    const float* gat2_ad = (const float*)d_in[12];
    const float* gat2_b  = (const float*)d_in[13];
    const float* dec_w1  = (const float*)d_in[14];
    const float* dec_b1  = (const float*)d_in[15];
    const float* dec_w2  = (const float*)d_in[16];
    const float* dec_b2  = (const float*)d_in[17];

    float* ws = (float*)d_ws;
    float* bufA  = ws;                                   // [N,64]
    float* bufB  = bufA + (size_t)NN * 64;               // [N,64]
    float* xl    = bufB + (size_t)NN * 64;               // [N,256]
    float* a_src = xl + (size_t)NN * 256;                // [N,4]
    float* a_dst = a_src + (size_t)NN * 4;               // [N,4]
    unsigned* m  = (unsigned*)(a_dst + (size_t)NN * 4);  // [N,4]
    float* ssum  = (float*)m + (size_t)NN * 4;           // [N,4]
    float4* alph = (float4*)(ssum + (size_t)NN * 4);     // [ETOT,4] floats

    // encoder
    gemm_kernel<<<dim3((NN + 63) / 64, 1), 256, 0, stream>>>(obs, enc_w1, enc_b1, bufA, NN, 128, 64, 1);
    gemm_kernel<<<dim3((NN + 63) / 64, 1), 256, 0, stream>>>(bufA, enc_w2, enc_b2, bufB, NN, 64, 64, 0);

    // GAT layers (in/out: bufB)
    gat_layer(bufB, gat1_w, gat1_as, gat1_ad, gat1_b, ei, xl, a_src, a_dst, m, ssum, alph, bufA, bufB, stream);
    gat_layer(bufB, gat2_w, gat2_as, gat2_ad, gat2_b, ei, xl, a_src, a_dst, m, ssum, alph, bufA, bufB, stream);

    // decoder
    gemm_kernel<<<dim3((NN + 63) / 64, 1), 256, 0, stream>>>(bufB, dec_w1, dec_b1, bufA, NN, 64, 64, 1);
    gemm_kernel<<<dim3((NN + 63) / 64, 1), 256, 0, stream>>>(bufA, dec_w2, dec_b2, (float*)d_out, NN, 64, 32, 0);
}

// Round 3
// 798.155 us; speedup vs baseline: 1.8581x; 1.7948x over previous
//
#include <hip/hip_runtime.h>
#include <math.h>

#define NN 100000
#define EE 800000
#define ETOT (EE + NN)
// HID=64, HEADS=4, OBS=128, ACT=32

// ---------------- GEMM: C[M,Nc] = A[M,K] @ B[K,Nc] (+bias, optional relu) ----------------
__global__ __launch_bounds__(256) void gemm_kernel(
    const float* __restrict__ A, const float* __restrict__ B,
    const float* __restrict__ bias, float* __restrict__ C,
    int M, int K, int Nc, int doRelu)
{
    __shared__ float sA[16][65];   // [k][row]
    __shared__ float sB[16][65];   // [k][col]

    const int bm = blockIdx.x * 64;
    const int bn = blockIdx.y * 64;
    const int tid = threadIdx.x;
    const int tx = tid & 15;
    const int ty = tid >> 4;

    float acc[4][4] = {};

    for (int k0 = 0; k0 < K; k0 += 16) {
#pragma unroll
        for (int i = 0; i < 4; ++i) {
            int idx = tid + i * 256;
            int r = idx >> 4;
            int c = idx & 15;
            int gr = bm + r;
            sA[c][r] = (gr < M) ? A[(size_t)gr * K + k0 + c] : 0.f;
        }
#pragma unroll
        for (int i = 0; i < 4; ++i) {
            int idx = tid + i * 256;
            int r = idx >> 6;
            int c = idx & 63;
            int gc = bn + c;
            sB[r][c] = (gc < Nc) ? B[(size_t)(k0 + r) * Nc + gc] : 0.f;
        }
        __syncthreads();
#pragma unroll
        for (int k = 0; k < 16; ++k) {
            float a[4], b[4];
#pragma unroll
            for (int i = 0; i < 4; ++i) a[i] = sA[k][ty * 4 + i];
#pragma unroll
            for (int j = 0; j < 4; ++j) b[j] = sB[k][tx * 4 + j];
#pragma unroll
            for (int i = 0; i < 4; ++i)
#pragma unroll
                for (int j = 0; j < 4; ++j) acc[i][j] += a[i] * b[j];
        }
        __syncthreads();
    }

#pragma unroll
    for (int i = 0; i < 4; ++i) {
        int gr = bm + ty * 4 + i;
        if (gr >= M) continue;
#pragma unroll
        for (int j = 0; j < 4; ++j) {
            int gc = bn + tx * 4 + j;
            if (gc >= Nc) continue;
            float v = acc[i][j] + (bias ? bias[gc] : 0.f);
            if (doRelu) v = fmaxf(v, 0.f);
            C[(size_t)gr * Nc + gc] = v;
        }
    }
}

// ---------------- attention scores ----------------
__global__ __launch_bounds__(256) void att_scores_kernel(
    const float* __restrict__ xl, const float* __restrict__ att_src,
    const float* __restrict__ att_dst, float* __restrict__ a_src,
    float* __restrict__ a_dst, int Nn)
{
    __shared__ float s_src[256], s_dst[256];
    int tid = threadIdx.x;
    s_src[tid] = att_src[tid];
    s_dst[tid] = att_dst[tid];
    __syncthreads();

    int gid = blockIdx.x * 256 + tid;
    if (gid >= Nn * 4) return;
    int n = gid >> 2, h = gid & 3;

    const float4* xp  = (const float4*)(xl + (size_t)n * 256 + h * 64);
    const float4* ap  = (const float4*)(s_src + h * 64);
    const float4* bp  = (const float4*)(s_dst + h * 64);
    float ss = 0.f, sd = 0.f;
#pragma unroll
    for (int i = 0; i < 16; ++i) {
        float4 v = xp[i], a = ap[i], b = bp[i];
        ss += v.x * a.x + v.y * a.y + v.z * a.z + v.w * a.w;
        sd += v.x * b.x + v.y * b.y + v.z * b.z + v.w * b.w;
    }
    a_src[gid] = ss;
    a_dst[gid] = sd;
}

__device__ __forceinline__ float lrelu(float x) { return x > 0.f ? x : 0.2f * x; }
__device__ __forceinline__ int edge_src(const int* ei, int e) { return e < EE ? ei[e] : e - EE; }
__device__ __forceinline__ int edge_dst(const int* ei, int e) { return e < EE ? ei[EE + e] : e - EE; }

// ================= CSR build =================
__global__ __launch_bounds__(256) void csr_count(const int* __restrict__ ei, int* __restrict__ cnt)
{
    int e = blockIdx.x * 256 + threadIdx.x;
    if (e >= ETOT) return;
    atomicAdd(&cnt[edge_dst(ei, e)], 1);
}

// partial sums of 512-element chunks
__global__ __launch_bounds__(256) void scan_partial(const int* __restrict__ cnt, int* __restrict__ partial)
{
    __shared__ int s[256];
    int b = blockIdx.x;
    int gi = b * 512 + threadIdx.x;
    int v = 0;
    if (gi < NN) v += cnt[gi];
    if (gi + 256 < NN) v += cnt[gi + 256];
    s[threadIdx.x] = v;
    __syncthreads();
    for (int off = 128; off > 0; off >>= 1) {
        if (threadIdx.x < off) s[threadIdx.x] += s[threadIdx.x + off];
        __syncthreads();
    }
    if (threadIdx.x == 0) partial[b] = s[0];
}

// exclusive scan of block partials (single block, Hillis-Steele over 256)
__global__ __launch_bounds__(256) void scan_top(int* __restrict__ partial, int nb)
{
    __shared__ int s[256];
    int tid = threadIdx.x;
    s[tid] = (tid < nb) ? partial[tid] : 0;
    __syncthreads();
    for (int off = 1; off < 256; off <<= 1) {
        int t = (tid >= off) ? s[tid - off] : 0;
        __syncthreads();
        s[tid] += t;
        __syncthreads();
    }
    if (tid < nb) partial[tid] = (tid == 0) ? 0 : s[tid - 1];
}

// exclusive scan within each 512 chunk (Blelloch) + add block offset
__global__ __launch_bounds__(256) void scan_final(
    const int* __restrict__ cnt, const int* __restrict__ partial, int* __restrict__ row_ptr)
{
    __shared__ int s[512];
    int b = blockIdx.x;
    int tid = threadIdx.x;
    int g0 = b * 512 + tid, g1 = b * 512 + tid + 256;
    s[tid]       = (g0 < NN) ? cnt[g0] : 0;
    s[tid + 256] = (g1 < NN) ? cnt[g1] : 0;
    __syncthreads();
#pragma unroll
    for (int d = 0; d < 9; ++d) {
        int stride = 1 << d, n = 256 >> d;
        if (tid < n) s[(2 * tid + 2) * stride - 1] += s[(2 * tid + 1) * stride - 1];
        __syncthreads();
    }
    if (tid == 0) s[511] = 0;
    __syncthreads();
#pragma unroll
    for (int d = 8; d >= 0; --d) {
        int stride = 1 << d, n = 256 >> d;
        if (tid < n) {
            int i1 = (2 * tid + 1) * stride - 1, i2 = (2 * tid + 2) * stride - 1;
            int t = s[i1];
            s[i1] = s[i2];
            s[i2] += t;
        }
        __syncthreads();
    }
    int off = partial[b];
    if (g0 < NN) row_ptr[g0] = s[tid] + off;
    if (g1 < NN) row_ptr[g1] = s[tid + 256] + off;
}

// copy row_ptr -> cursor, set row_ptr[NN]
__global__ __launch_bounds__(256) void cursor_init(const int* __restrict__ row_ptr, int* __restrict__ cur)
{
    int i = blockIdx.x * 256 + threadIdx.x;
    if (i < NN) cur[i] = row_ptr[i];
    if (i == 0) ((int*)row_ptr)[NN] = ETOT;
}

__global__ __launch_bounds__(256) void csr_fill(
    const int* __restrict__ ei, int* __restrict__ cur, int* __restrict__ col_src)
{
    int e = blockIdx.x * 256 + threadIdx.x;
    if (e >= ETOT) return;
    int d = edge_dst(ei, e);
    int pos = atomicAdd(&cur[d], 1);
    col_src[pos] = edge_src(ei, e);
}

// ================= per-layer softmax over CSR rows (thread per dst) =================
__global__ __launch_bounds__(256) void row_softmax(
    const int* __restrict__ row_ptr, const int* __restrict__ col_src,
    const float* __restrict__ a_src, const float* __restrict__ a_dst,
    float4* __restrict__ w)
{
    int d = blockIdx.x * 256 + threadIdx.x;
    if (d >= NN) return;
    int rs = row_ptr[d], re = row_ptr[d + 1];
    float4 ad = ((const float4*)a_dst)[d];
    float mx = -1e30f, my = -1e30f, mz = -1e30f, mw = -1e30f;
    for (int e = rs; e < re; ++e) {
        int s = col_src[e];
        float4 as = ((const float4*)a_src)[s];
        float4 al;
        al.x = lrelu(as.x + ad.x);
        al.y = lrelu(as.y + ad.y);
        al.z = lrelu(as.z + ad.z);
        al.w = lrelu(as.w + ad.w);
        w[e] = al;
        mx = fmaxf(mx, al.x); my = fmaxf(my, al.y);
        mz = fmaxf(mz, al.z); mw = fmaxf(mw, al.w);
    }
    float sx = 0.f, sy = 0.f, sz = 0.f, sw = 0.f;
    for (int e = rs; e < re; ++e) {
        float4 al = w[e];
        al.x = expf(al.x - mx); al.y = expf(al.y - my);
        al.z = expf(al.z - mz); al.w = expf(al.w - mw);
        w[e] = al;
        sx += al.x; sy += al.y; sz += al.z; sw += al.w;
    }
    sx = 0.25f / sx; sy = 0.25f / sy; sz = 0.25f / sz; sw = 0.25f / sw;
    for (int e = rs; e < re; ++e) {
        float4 p = w[e];
        p.x *= sx; p.y *= sy; p.z *= sz; p.w *= sw;
        w[e] = p;
    }
}

// ================= gather aggregation (wave per dst) + bias + relu =================
__global__ __launch_bounds__(256) void gather_agg(
    const int* __restrict__ row_ptr, const int* __restrict__ col_src,
    const float4* __restrict__ w, const float* __restrict__ xl,
    const float* __restrict__ bias, float* __restrict__ out)
{
    int d = (blockIdx.x * 256 + threadIdx.x) >> 6;  // wave per dst
    int lane = threadIdx.x & 63;
    if (d >= NN) return;
    int rs = row_ptr[d], re = row_ptr[d + 1];
    float acc = 0.f;
    for (int e = rs; e < re; ++e) {
        float4 wv = w[e];                 // wave-uniform -> broadcast
        int s = col_src[e];               // wave-uniform
        const float* xp = xl + (size_t)s * 256;
        acc += xp[lane] * wv.x + xp[64 + lane] * wv.y
             + xp[128 + lane] * wv.z + xp[192 + lane] * wv.w;
    }
    out[(size_t)d * 64 + lane] = fmaxf(acc + bias[lane], 0.f);
}

// ---------------- host-side GAT layer ----------------
static void gat_layer(const float* x, const float* W, const float* attS, const float* attD,
                      const float* b, const int* row_ptr, const int* col_src,
                      float* xl, float* a_src, float* a_dst, float4* w,
                      float* xout, hipStream_t stream)
{
    gemm_kernel<<<dim3((NN + 63) / 64, 4), 256, 0, stream>>>(x, W, nullptr, xl, NN, 64, 256, 0);
    att_scores_kernel<<<(NN * 4 + 255) / 256, 256, 0, stream>>>(xl, attS, attD, a_src, a_dst, NN);
    row_softmax<<<(NN + 255) / 256, 256, 0, stream>>>(row_ptr, col_src, a_src, a_dst, w);
    gather_agg<<<(NN * 64 + 255) / 256, 256, 0, stream>>>(row_ptr, col_src, w, xl, b, xout);
}

extern "C" void kernel_launch(void* const* d_in, const int* in_sizes, int n_in,
                              void* d_out, int out_size, void* d_ws, size_t ws_size,
                              hipStream_t stream)
{
    const float* obs     = (const float*)d_in[0];
    const int*   ei      = (const int*)d_in[1];
    const float* enc_w1  = (const float*)d_in[2];
    const float* enc_b1  = (const float*)d_in[3];
    const float* enc_w2  = (const float*)d_in[4];
    const float* enc_b2  = (const float*)d_in[5];
    const float* gat1_w  = (const float*)d_in[6];
    const float* gat1_as = (const float*)d_in[7];
    const float* gat1_ad = (const float*)d_in[8];
    const float* gat1_b  = (const float*)d_in[9];
    const float* gat2_w  = (const float*)d_in[10];
    const float* gat2_as = (const float*)d_in[11];
    const float* gat2_ad = (const float*)d_in[12];
    const float* gat2_b  = (const float*)d_in[13];
    const float* dec_w1  = (const float*)d_in[14];
    const float* dec_b1  = (const float*)d_in[15];
    const float* dec_w2  = (const float*)d_in[16];
    const float* dec_b2  = (const float*)d_in[17];

    float* ws = (float*)d_ws;
    float* bufA    = ws;                                   // [N,64]
    float* bufB    = bufA + (size_t)NN * 64;               // [N,64]
    float* xl      = bufB + (size_t)NN * 64;               // [N,256]
    float* a_src   = xl + (size_t)NN * 256;                // [N,4]
    float* a_dst   = a_src + (size_t)NN * 4;               // [N,4]
    float4* w      = (float4*)(a_dst + (size_t)NN * 4);    // [ETOT] float4
    int* row_ptr   = (int*)(w + (size_t)ETOT);             // [N+1]
    int* cnt       = row_ptr + NN + 4;                     // [N]
    int* cur       = cnt + NN;                             // [N]
    int* col_src   = cur + NN;                             // [ETOT]
    int* partial   = col_src + ETOT;                       // [256]

    const int NB = (NN + 511) / 512;  // 196 chunks

    // ---- CSR build (once, reused by both GAT layers) ----
    hipMemsetAsync(cnt, 0, (size_t)NN * sizeof(int), stream);
    csr_count<<<(ETOT + 255) / 256, 256, 0, stream>>>(ei, cnt);
    scan_partial<<<NB, 256, 0, stream>>>(cnt, partial);
    scan_top<<<1, 256, 0, stream>>>(partial, NB);
    scan_final<<<NB, 256, 0, stream>>>(cnt, partial, row_ptr);
    cursor_init<<<(NN + 255) / 256, 256, 0, stream>>>(row_ptr, cur);
    csr_fill<<<(ETOT + 255) / 256, 256, 0, stream>>>(ei, cur, col_src);

    // ---- encoder ----
    gemm_kernel<<<dim3((NN + 63) / 64, 1), 256, 0, stream>>>(obs, enc_w1, enc_b1, bufA, NN, 128, 64, 1);
    gemm_kernel<<<dim3((NN + 63) / 64, 1), 256, 0, stream>>>(bufA, enc_w2, enc_b2, bufB, NN, 64, 64, 0);

    // ---- GAT layers (in/out: bufB) ----
    gat_layer(bufB, gat1_w, gat1_as, gat1_ad, gat1_b, row_ptr, col_src, xl, a_src, a_dst, w, bufB, stream);
    gat_layer(bufB, gat2_w, gat2_as, gat2_ad, gat2_b, row_ptr, col_src, xl, a_src, a_dst, w, bufB, stream);

    // ---- decoder ----
    gemm_kernel<<<dim3((NN + 63) / 64, 1), 256, 0, stream>>>(bufB, dec_w1, dec_b1, bufA, NN, 64, 64, 1);
    gemm_kernel<<<dim3((NN + 63) / 64, 1), 256, 0, stream>>>(bufA, dec_w2, dec_b2, (float*)d_out, NN, 64, 32, 0);
}

// Round 5
// 735.724 us; speedup vs baseline: 2.0157x; 1.0849x over previous
//
#include <hip/hip_runtime.h>
#include <math.h>

#define NN 100000
#define EE 800000
#define ETOT (EE + NN)
// HID=64, HEADS=4, OBS=128, ACT=32

// ---------------- GEMM: C[M,Nc] = A[M,K] @ B[K,Nc] (+bias, optional relu) ----------------
__global__ __launch_bounds__(256) void gemm_kernel(
    const float* __restrict__ A, const float* __restrict__ B,
    const float* __restrict__ bias, float* __restrict__ C,
    int M, int K, int Nc, int doRelu)
{
    __shared__ float sA[16][65];   // [k][row]
    __shared__ float sB[16][65];   // [k][col]

    const int bm = blockIdx.x * 64;
    const int bn = blockIdx.y * 64;
    const int tid = threadIdx.x;
    const int tx = tid & 15;
    const int ty = tid >> 4;

    float acc[4][4] = {};

    for (int k0 = 0; k0 < K; k0 += 16) {
#pragma unroll
        for (int i = 0; i < 4; ++i) {
            int idx = tid + i * 256;
            int r = idx >> 4;
            int c = idx & 15;
            int gr = bm + r;
            sA[c][r] = (gr < M) ? A[(size_t)gr * K + k0 + c] : 0.f;
        }
#pragma unroll
        for (int i = 0; i < 4; ++i) {
            int idx = tid + i * 256;
            int r = idx >> 6;
            int c = idx & 63;
            int gc = bn + c;
            sB[r][c] = (gc < Nc) ? B[(size_t)(k0 + r) * Nc + gc] : 0.f;
        }
        __syncthreads();
#pragma unroll
        for (int k = 0; k < 16; ++k) {
            float a[4], b[4];
#pragma unroll
            for (int i = 0; i < 4; ++i) a[i] = sA[k][ty * 4 + i];
#pragma unroll
            for (int j = 0; j < 4; ++j) b[j] = sB[k][tx * 4 + j];
#pragma unroll
            for (int i = 0; i < 4; ++i)
#pragma unroll
                for (int j = 0; j < 4; ++j) acc[i][j] += a[i] * b[j];
        }
        __syncthreads();
    }

#pragma unroll
    for (int i = 0; i < 4; ++i) {
        int gr = bm + ty * 4 + i;
        if (gr >= M) continue;
#pragma unroll
        for (int j = 0; j < 4; ++j) {
            int gc = bn + tx * 4 + j;
            if (gc >= Nc) continue;
            float v = acc[i][j] + (bias ? bias[gc] : 0.f);
            if (doRelu) v = fmaxf(v, 0.f);
            C[(size_t)gr * Nc + gc] = v;
        }
    }
}

__device__ __forceinline__ float lrelu(float x) { return x > 0.f ? x : 0.2f * x; }
__device__ __forceinline__ int edge_src(const int* ei, int e) { return e < EE ? ei[e] : e - EE; }
__device__ __forceinline__ int edge_dst(const int* ei, int e) { return e < EE ? ei[EE + e] : e - EE; }

// ================= CSR build =================
__global__ __launch_bounds__(256) void csr_count(const int* __restrict__ ei, int* __restrict__ cnt)
{
    int e = blockIdx.x * 256 + threadIdx.x;
    if (e >= ETOT) return;
    atomicAdd(&cnt[edge_dst(ei, e)], 1);
}

__global__ __launch_bounds__(256) void scan_partial(const int* __restrict__ cnt, int* __restrict__ partial)
{
    __shared__ int s[256];
    int b = blockIdx.x;
    int gi = b * 512 + threadIdx.x;
    int v = 0;
    if (gi < NN) v += cnt[gi];
    if (gi + 256 < NN) v += cnt[gi + 256];
    s[threadIdx.x] = v;
    __syncthreads();
    for (int off = 128; off > 0; off >>= 1) {
        if (threadIdx.x < off) s[threadIdx.x] += s[threadIdx.x + off];
        __syncthreads();
    }
    if (threadIdx.x == 0) partial[b] = s[0];
}

__global__ __launch_bounds__(256) void scan_top(int* __restrict__ partial, int nb)
{
    __shared__ int s[256];
    int tid = threadIdx.x;
    s[tid] = (tid < nb) ? partial[tid] : 0;
    __syncthreads();
    for (int off = 1; off < 256; off <<= 1) {
        int t = (tid >= off) ? s[tid - off] : 0;
        __syncthreads();
        s[tid] += t;
        __syncthreads();
    }
    if (tid < nb) partial[tid] = (tid == 0) ? 0 : s[tid - 1];
}

__global__ __launch_bounds__(256) void scan_final(
    const int* __restrict__ cnt, const int* __restrict__ partial, int* __restrict__ row_ptr)
{
    __shared__ int s[512];
    int b = blockIdx.x;
    int tid = threadIdx.x;
    int g0 = b * 512 + tid, g1 = b * 512 + tid + 256;
    s[tid]       = (g0 < NN) ? cnt[g0] : 0;
    s[tid + 256] = (g1 < NN) ? cnt[g1] : 0;
    __syncthreads();
#pragma unroll
    for (int d = 0; d < 9; ++d) {
        int stride = 1 << d, n = 256 >> d;
        if (tid < n) s[(2 * tid + 2) * stride - 1] += s[(2 * tid + 1) * stride - 1];
        __syncthreads();
    }
    if (tid == 0) s[511] = 0;
    __syncthreads();
#pragma unroll
    for (int d = 8; d >= 0; --d) {
        int stride = 1 << d, n = 256 >> d;
        if (tid < n) {
            int i1 = (2 * tid + 1) * stride - 1, i2 = (2 * tid + 2) * stride - 1;
            int t = s[i1];
            s[i1] = s[i2];
            s[i2] += t;
        }
        __syncthreads();
    }
    int off = partial[b];
    if (g0 < NN) row_ptr[g0] = s[tid] + off;
    if (g1 < NN) row_ptr[g1] = s[tid + 256] + off;
}

__global__ __launch_bounds__(256) void cursor_init(const int* __restrict__ row_ptr, int* __restrict__ cur)
{
    int i = blockIdx.x * 256 + threadIdx.x;
    if (i < NN) cur[i] = row_ptr[i];
    if (i == 0) ((int*)row_ptr)[NN] = ETOT;
}

__global__ __launch_bounds__(256) void csr_fill(
    const int* __restrict__ ei, int* __restrict__ cur, int* __restrict__ col_src)
{
    int e = blockIdx.x * 256 + threadIdx.x;
    if (e >= ETOT) return;
    int d = edge_dst(ei, e);
    int pos = atomicAdd(&cur[d], 1);
    col_src[pos] = edge_src(ei, e);
}

// ================= per-layer weight precomputes =================
// vs[k*4+h] = sum_j W[k,h*64+j]*attS[h,j]; vd likewise (one block, 256 threads)
__global__ __launch_bounds__(256) void att_vec_kernel(
    const float* __restrict__ W, const float* __restrict__ attS,
    const float* __restrict__ attD, float* __restrict__ vs, float* __restrict__ vd)
{
    int tid = threadIdx.x;           // tid = k*4+h
    int k = tid >> 2, h = tid & 3;
    const float* wr = W + (size_t)k * 256 + h * 64;
    const float* as = attS + h * 64;
    const float* ad = attD + h * 64;
    float ss = 0.f, sd = 0.f;
#pragma unroll
    for (int j = 0; j < 64; ++j) {
        float wv = wr[j];
        ss += wv * as[j];
        sd += wv * ad[j];
    }
    vs[tid] = ss;
    vd[tid] = sd;
}

// B2[(h*64+k)*64+j] = W[k*256 + h*64 + j]
__global__ __launch_bounds__(256) void permW_kernel(const float* __restrict__ W, float* __restrict__ B2)
{
    int i = blockIdx.x * 256 + threadIdx.x;   // i = r*64+j, r = h*64+k
    if (i >= 256 * 64) return;
    int r = i >> 6, j = i & 63;
    int h = r >> 6, k = r & 63;
    B2[i] = W[(size_t)k * 256 + h * 64 + j];
}

// ================= attention scores directly from x =================
__global__ __launch_bounds__(256) void scores_x_kernel(
    const float* __restrict__ x, const float* __restrict__ vs,
    const float* __restrict__ vd, float4* __restrict__ a4s, float4* __restrict__ a4d)
{
    __shared__ float4 svs[64], svd[64];
    int tid = threadIdx.x;
    if (tid < 64) {
        svs[tid] = ((const float4*)vs)[tid];
        svd[tid] = ((const float4*)vd)[tid];
    }
    __syncthreads();
    int n = blockIdx.x * 256 + tid;
    if (n >= NN) return;
    const float4* xp = (const float4*)(x + (size_t)n * 64);
    float4 as = {0.f, 0.f, 0.f, 0.f}, ad = {0.f, 0.f, 0.f, 0.f};
#pragma unroll
    for (int i = 0; i < 16; ++i) {
        float4 xv = xp[i];
        float4 s0 = svs[i * 4 + 0], s1 = svs[i * 4 + 1], s2 = svs[i * 4 + 2], s3 = svs[i * 4 + 3];
        float4 d0 = svd[i * 4 + 0], d1 = svd[i * 4 + 1], d2 = svd[i * 4 + 2], d3 = svd[i * 4 + 3];
        as.x += xv.x * s0.x + xv.y * s1.x + xv.z * s2.x + xv.w * s3.x;
        as.y += xv.x * s0.y + xv.y * s1.y + xv.z * s2.y + xv.w * s3.y;
        as.z += xv.x * s0.z + xv.y * s1.z + xv.z * s2.z + xv.w * s3.z;
        as.w += xv.x * s0.w + xv.y * s1.w + xv.z * s2.w + xv.w * s3.w;
        ad.x += xv.x * d0.x + xv.y * d1.x + xv.z * d2.x + xv.w * d3.x;
        ad.y += xv.x * d0.y + xv.y * d1.y + xv.z * d2.y + xv.w * d3.y;
        ad.z += xv.x * d0.z + xv.y * d1.z + xv.z * d2.z + xv.w * d3.z;
        ad.w += xv.x * d0.w + xv.y * d1.w + xv.z * d2.w + xv.w * d3.w;
    }
    a4s[n] = as;
    a4d[n] = ad;
}

// ================= softmax (alpha/max/exp/sum) per CSR row; stores p and inv =================
__global__ __launch_bounds__(256) void row_softmax(
    const int* __restrict__ row_ptr, const int* __restrict__ col_src,
    const float4* __restrict__ a4s, const float4* __restrict__ a4d,
    float4* __restrict__ w, float4* __restrict__ inv)
{
    int d = blockIdx.x * 256 + threadIdx.x;
    if (d >= NN) return;
    int rs = row_ptr[d], re = row_ptr[d + 1];
    float4 ad = a4d[d];
    float mx = -1e30f, my = -1e30f, mz = -1e30f, mw = -1e30f;
    for (int e = rs; e < re; ++e) {
        int s = col_src[e];
        float4 as = a4s[s];
        float4 al;
        al.x = lrelu(as.x + ad.x);
        al.y = lrelu(as.y + ad.y);
        al.z = lrelu(as.z + ad.z);
        al.w = lrelu(as.w + ad.w);
        w[e] = al;
        mx = fmaxf(mx, al.x); my = fmaxf(my, al.y);
        mz = fmaxf(mz, al.z); mw = fmaxf(mw, al.w);
    }
    float sx = 0.f, sy = 0.f, sz = 0.f, sw = 0.f;
    for (int e = rs; e < re; ++e) {
        float4 al = w[e];
        al.x = expf(al.x - mx); al.y = expf(al.y - my);
        al.z = expf(al.z - mz); al.w = expf(al.w - mw);
        w[e] = al;
        sx += al.x; sy += al.y; sz += al.z; sw += al.w;
    }
    float4 iv;
    iv.x = 0.25f / sx; iv.y = 0.25f / sy; iv.z = 0.25f / sz; iv.w = 0.25f / sw;
    inv[d] = iv;
}

// ================= gather aggregation in x-space (wave per dst) =================
// agg[d, h*64+lane] = inv[d,h] * sum_e p[e,h] * x[src_e, lane]
__global__ __launch_bounds__(256) void gather_agg_x(
    const int* __restrict__ row_ptr, const int* __restrict__ col_src,
    const float4* __restrict__ w, const float4* __restrict__ inv,
    const float* __restrict__ x, float* __restrict__ agg)
{
    int d = (blockIdx.x * 256 + threadIdx.x) >> 6;
    int lane = threadIdx.x & 63;
    if (d >= NN) return;
    int rs = row_ptr[d], re = row_ptr[d + 1];
    float a0 = 0.f, a1 = 0.f, a2 = 0.f, a3 = 0.f;
    for (int e = rs; e < re; ++e) {
        float4 pv = w[e];                       // wave-uniform broadcast
        int s = col_src[e];                     // wave-uniform
        float xv = x[(size_t)s * 64 + lane];    // one 256B wave load
        a0 += pv.x * xv; a1 += pv.y * xv; a2 += pv.z * xv; a3 += pv.w * xv;
    }
    float4 iv = inv[d];
    float* op = agg + (size_t)d * 256;
    op[lane]       = a0 * iv.x;
    op[64 + lane]  = a1 * iv.y;
    op[128 + lane] = a2 * iv.z;
    op[192 + lane] = a3 * iv.w;
}

// ---------------- host-side GAT layer ----------------
static void gat_layer(float* x /* in/out [N,64] */, const float* W, const float* attS,
                      const float* attD, const float* b, const int* row_ptr, const int* col_src,
                      float* agg, float4* a4s, float4* a4d, float4* inv, float4* w,
                      float* vs, float* vd, float* B2, hipStream_t stream)
{
    att_vec_kernel<<<1, 256, 0, stream>>>(W, attS, attD, vs, vd);
    permW_kernel<<<64, 256, 0, stream>>>(W, B2);
    scores_x_kernel<<<(NN + 255) / 256, 256, 0, stream>>>(x, vs, vd, a4s, a4d);
    row_softmax<<<(NN + 255) / 256, 256, 0, stream>>>(row_ptr, col_src, a4s, a4d, w, inv);
    gather_agg_x<<<(NN * 64 + 255) / 256, 256, 0, stream>>>(row_ptr, col_src, w, inv, x, agg);
    // x_out = relu(agg @ B2 + b)   (0.25 folded into inv)
    gemm_kernel<<<dim3((NN + 63) / 64, 1), 256, 0, stream>>>(agg, B2, b, x, NN, 256, 64, 1);
}

extern "C" void kernel_launch(void* const* d_in, const int* in_sizes, int n_in,
                              void* d_out, int out_size, void* d_ws, size_t ws_size,
                              hipStream_t stream)
{
    const float* obs     = (const float*)d_in[0];
    const int*   ei      = (const int*)d_in[1];
    const float* enc_w1  = (const float*)d_in[2];
    const float* enc_b1  = (const float*)d_in[3];
    const float* enc_w2  = (const float*)d_in[4];
    const float* enc_b2  = (const float*)d_in[5];
    const float* gat1_w  = (const float*)d_in[6];
    const float* gat1_as = (const float*)d_in[7];
    const float* gat1_ad = (const float*)d_in[8];
    const float* gat1_b  = (const float*)d_in[9];
    const float* gat2_w  = (const float*)d_in[10];
    const float* gat2_as = (const float*)d_in[11];
    const float* gat2_ad = (const float*)d_in[12];
    const float* gat2_b  = (const float*)d_in[13];
    const float* dec_w1  = (const float*)d_in[14];
    const float* dec_b1  = (const float*)d_in[15];
    const float* dec_w2  = (const float*)d_in[16];
    const float* dec_b2  = (const float*)d_in[17];

    float* ws = (float*)d_ws;
    float* bufA    = ws;                                   // [N,64]
    float* bufB    = bufA + (size_t)NN * 64;               // [N,64]  (x)
    float* agg     = bufB + (size_t)NN * 64;               // [N,256]
    float4* a4s    = (float4*)(agg + (size_t)NN * 256);    // [N]
    float4* a4d    = a4s + NN;                             // [N]
    float4* inv    = a4d + NN;                             // [N]
    float4* w      = inv + NN;                             // [ETOT]
    int* row_ptr   = (int*)(w + (size_t)ETOT);             // [N+1] (+pad)
    int* cnt       = row_ptr + NN + 4;                     // [N]
    int* cur       = cnt + NN;                             // [N]
    int* col_src   = cur + NN;                             // [ETOT]
    int* partial   = col_src + ETOT;                       // [256]
    float* vs      = (float*)(partial + 256);              // [256]
    float* vd      = vs + 256;                             // [256]
    float* B2      = vd + 256;                             // [256*64]

    const int NB = (NN + 511) / 512;

    // ---- CSR build (once, reused by both GAT layers) ----
    hipMemsetAsync(cnt, 0, (size_t)NN * sizeof(int), stream);
    csr_count<<<(ETOT + 255) / 256, 256, 0, stream>>>(ei, cnt);
    scan_partial<<<NB, 256, 0, stream>>>(cnt, partial);
    scan_top<<<1, 256, 0, stream>>>(partial, NB);
    scan_final<<<NB, 256, 0, stream>>>(cnt, partial, row_ptr);
    cursor_init<<<(NN + 255) / 256, 256, 0, stream>>>(row_ptr, cur);
    csr_fill<<<(ETOT + 255) / 256, 256, 0, stream>>>(ei, cur, col_src);

    // ---- encoder ----
    gemm_kernel<<<dim3((NN + 63) / 64, 1), 256, 0, stream>>>(obs, enc_w1, enc_b1, bufA, NN, 128, 64, 1);
    gemm_kernel<<<dim3((NN + 63) / 64, 1), 256, 0, stream>>>(bufA, enc_w2, enc_b2, bufB, NN, 64, 64, 0);

    // ---- GAT layers (x lives in bufB) ----
    gat_layer(bufB, gat1_w, gat1_as, gat1_ad, gat1_b, row_ptr, col_src, agg, a4s, a4d, inv, w, vs, vd, B2, stream);
    gat_layer(bufB, gat2_w, gat2_as, gat2_ad, gat2_b, row_ptr, col_src, agg, a4s, a4d, inv, w, vs, vd, B2, stream);

    // ---- decoder ----
    gemm_kernel<<<dim3((NN + 63) / 64, 1), 256, 0, stream>>>(bufB, dec_w1, dec_b1, bufA, NN, 64, 64, 1);
    gemm_kernel<<<dim3((NN + 63) / 64, 1), 256, 0, stream>>>(bufA, dec_w2, dec_b2, (float*)d_out, NN, 64, 32, 0);
}

// Round 6
// 621.881 us; speedup vs baseline: 2.3847x; 1.1831x over previous
//
#include <hip/hip_runtime.h>
#include <math.h>

#define NN 100000
#define EE 800000
#define ETOT (EE + NN)
// HID=64, HEADS=4, OBS=128, ACT=32

// ---------------- GEMM: C[M,Nc] = A[M,K] @ B[K,Nc] (+bias, optional relu) ----------------
// 256x32 tile, 8x4 micro-tile, BK=16. 256 threads: ty=tid>>3 (0..31) row group,
// tx=tid&7 (0..7) col group. Rows: ty*4+{0..3} and 128+ty*4+{0..3}; cols bn+tx*4+{0..3}.
// sA stride 260 floats: 16B-aligned rows, transpose-write 2-way (free), b128 reads
// conflict-free (8 distinct ty per wave -> 8 distinct bank-quads).
__global__ __launch_bounds__(256) void gemm_kernel(
    const float* __restrict__ A, const float* __restrict__ B,
    const float* __restrict__ bias, float* __restrict__ C,
    int M, int K, int Nc, int doRelu)
{
    __shared__ __align__(16) float sA[16 * 260];   // [k][row 0..255], stride 260
    __shared__ __align__(16) float sB[16 * 36];    // [k][col 0..31], stride 36

    const int bm = blockIdx.x * 256;
    const int bn = blockIdx.y * 32;
    const int tid = threadIdx.x;
    const int ty = tid >> 3;   // 0..31
    const int tx = tid & 7;    // 0..7

    float acc[8][4] = {};

    for (int k0 = 0; k0 < K; k0 += 16) {
        // ---- stage A: 256 rows x 16 k (transpose to [k][row]) ----
#pragma unroll
        for (int j = 0; j < 4; ++j) {
            int row = j * 64 + (tid >> 2);   // 0..255
            int cw  = tid & 3;               // which float4 of the 16-k strip
            int gr  = bm + row;
            float4 v = {0.f, 0.f, 0.f, 0.f};
            if (gr < M) v = *(const float4*)&A[(size_t)gr * K + k0 + cw * 4];
            sA[(cw * 4 + 0) * 260 + row] = v.x;
            sA[(cw * 4 + 1) * 260 + row] = v.y;
            sA[(cw * 4 + 2) * 260 + row] = v.z;
            sA[(cw * 4 + 3) * 260 + row] = v.w;
        }
        // ---- stage B: 16 k x 32 cols (first 128 threads) ----
        if (tid < 128) {
            int row = tid >> 3;      // 0..15
            int c4  = tid & 7;       // 0..7
            float4 v = {0.f, 0.f, 0.f, 0.f};
            if (bn + c4 * 4 < Nc) v = *(const float4*)&B[(size_t)(k0 + row) * Nc + bn + c4 * 4];
            *(float4*)&sB[row * 36 + c4 * 4] = v;
        }
        __syncthreads();
#pragma unroll
        for (int k = 0; k < 16; ++k) {
            float4 a0 = *(const float4*)&sA[k * 260 + ty * 4];
            float4 a1 = *(const float4*)&sA[k * 260 + 128 + ty * 4];
            float4 b0 = *(const float4*)&sB[k * 36 + tx * 4];
            float a[8] = {a0.x, a0.y, a0.z, a0.w, a1.x, a1.y, a1.z, a1.w};
            float b[4] = {b0.x, b0.y, b0.z, b0.w};
#pragma unroll
            for (int i = 0; i < 8; ++i)
#pragma unroll
                for (int j2 = 0; j2 < 4; ++j2) acc[i][j2] += a[i] * b[j2];
        }
        __syncthreads();
    }

    // ---- epilogue: bias + relu, float4 stores ----
    float bv[4] = {0.f, 0.f, 0.f, 0.f};
    int gc = bn + tx * 4;
    if (bias && gc < Nc) {
        bv[0] = bias[gc + 0]; bv[1] = bias[gc + 1];
        bv[2] = bias[gc + 2]; bv[3] = bias[gc + 3];
    }
#pragma unroll
    for (int ic = 0; ic < 2; ++ic) {
#pragma unroll
        for (int i = 0; i < 4; ++i) {
            int gr = bm + ic * 128 + ty * 4 + i;
            if (gr >= M || gc >= Nc) continue;
            float4 v;
            v.x = acc[ic * 4 + i][0] + bv[0];
            v.y = acc[ic * 4 + i][1] + bv[1];
            v.z = acc[ic * 4 + i][2] + bv[2];
            v.w = acc[ic * 4 + i][3] + bv[3];
            if (doRelu) {
                v.x = fmaxf(v.x, 0.f); v.y = fmaxf(v.y, 0.f);
                v.z = fmaxf(v.z, 0.f); v.w = fmaxf(v.w, 0.f);
            }
            *(float4*)&C[(size_t)gr * Nc + gc] = v;
        }
    }
}

__device__ __forceinline__ float lrelu(float x) { return x > 0.f ? x : 0.2f * x; }
__device__ __forceinline__ int edge_src(const int* ei, int e) { return e < EE ? ei[e] : e - EE; }
__device__ __forceinline__ int edge_dst(const int* ei, int e) { return e < EE ? ei[EE + e] : e - EE; }

// ================= CSR build =================
__global__ __launch_bounds__(256) void csr_count(const int* __restrict__ ei, int* __restrict__ cnt)
{
    int e = blockIdx.x * 256 + threadIdx.x;
    if (e >= ETOT) return;
    atomicAdd(&cnt[edge_dst(ei, e)], 1);
}

__global__ __launch_bounds__(256) void scan_partial(const int* __restrict__ cnt, int* __restrict__ partial)
{
    __shared__ int s[256];
    int b = blockIdx.x;
    int gi = b * 512 + threadIdx.x;
    int v = 0;
    if (gi < NN) v += cnt[gi];
    if (gi + 256 < NN) v += cnt[gi + 256];
    s[threadIdx.x] = v;
    __syncthreads();
    for (int off = 128; off > 0; off >>= 1) {
        if (threadIdx.x < off) s[threadIdx.x] += s[threadIdx.x + off];
        __syncthreads();
    }
    if (threadIdx.x == 0) partial[b] = s[0];
}

__global__ __launch_bounds__(256) void scan_top(int* __restrict__ partial, int nb)
{
    __shared__ int s[256];
    int tid = threadIdx.x;
    s[tid] = (tid < nb) ? partial[tid] : 0;
    __syncthreads();
    for (int off = 1; off < 256; off <<= 1) {
        int t = (tid >= off) ? s[tid - off] : 0;
        __syncthreads();
        s[tid] += t;
        __syncthreads();
    }
    if (tid < nb) partial[tid] = (tid == 0) ? 0 : s[tid - 1];
}

__global__ __launch_bounds__(256) void scan_final(
    const int* __restrict__ cnt, const int* __restrict__ partial, int* __restrict__ row_ptr)
{
    __shared__ int s[512];
    int b = blockIdx.x;
    int tid = threadIdx.x;
    int g0 = b * 512 + tid, g1 = b * 512 + tid + 256;
    s[tid]       = (g0 < NN) ? cnt[g0] : 0;
    s[tid + 256] = (g1 < NN) ? cnt[g1] : 0;
    __syncthreads();
#pragma unroll
    for (int d = 0; d < 9; ++d) {
        int stride = 1 << d, n = 256 >> d;
        if (tid < n) s[(2 * tid + 2) * stride - 1] += s[(2 * tid + 1) * stride - 1];
        __syncthreads();
    }
    if (tid == 0) s[511] = 0;
    __syncthreads();
#pragma unroll
    for (int d = 8; d >= 0; --d) {
        int stride = 1 << d, n = 256 >> d;
        if (tid < n) {
            int i1 = (2 * tid + 1) * stride - 1, i2 = (2 * tid + 2) * stride - 1;
            int t = s[i1];
            s[i1] = s[i2];
            s[i2] += t;
        }
        __syncthreads();
    }
    int off = partial[b];
    if (g0 < NN) row_ptr[g0] = s[tid] + off;
    if (g1 < NN) row_ptr[g1] = s[tid + 256] + off;
}

__global__ __launch_bounds__(256) void cursor_init(const int* __restrict__ row_ptr, int* __restrict__ cur)
{
    int i = blockIdx.x * 256 + threadIdx.x;
    if (i < NN) cur[i] = row_ptr[i];
    if (i == 0) ((int*)row_ptr)[NN] = ETOT;
}

__global__ __launch_bounds__(256) void csr_fill(
    const int* __restrict__ ei, int* __restrict__ cur, int* __restrict__ col_src)
{
    int e = blockIdx.x * 256 + threadIdx.x;
    if (e >= ETOT) return;
    int d = edge_dst(ei, e);
    int pos = atomicAdd(&cur[d], 1);
    col_src[pos] = edge_src(ei, e);
}

// ================= per-layer weight precomputes =================
__global__ __launch_bounds__(256) void att_vec_kernel(
    const float* __restrict__ W, const float* __restrict__ attS,
    const float* __restrict__ attD, float* __restrict__ vs, float* __restrict__ vd)
{
    int tid = threadIdx.x;           // tid = k*4+h
    int k = tid >> 2, h = tid & 3;
    const float* wr = W + (size_t)k * 256 + h * 64;
    const float* as = attS + h * 64;
    const float* ad = attD + h * 64;
    float ss = 0.f, sd = 0.f;
#pragma unroll
    for (int j = 0; j < 64; ++j) {
        float wv = wr[j];
        ss += wv * as[j];
        sd += wv * ad[j];
    }
    vs[tid] = ss;
    vd[tid] = sd;
}

// B2[(h*64+k)*64+j] = W[k*256 + h*64 + j]
__global__ __launch_bounds__(256) void permW_kernel(const float* __restrict__ W, float* __restrict__ B2)
{
    int i = blockIdx.x * 256 + threadIdx.x;   // i = r*64+j, r = h*64+k
    if (i >= 256 * 64) return;
    int r = i >> 6, j = i & 63;
    int h = r >> 6, k = r & 63;
    B2[i] = W[(size_t)k * 256 + h * 64 + j];
}

// ================= attention scores directly from x =================
__global__ __launch_bounds__(256) void scores_x_kernel(
    const float* __restrict__ x, const float* __restrict__ vs,
    const float* __restrict__ vd, float4* __restrict__ a4s, float4* __restrict__ a4d)
{
    __shared__ float4 svs[64], svd[64];
    int tid = threadIdx.x;
    if (tid < 64) {
        svs[tid] = ((const float4*)vs)[tid];
        svd[tid] = ((const float4*)vd)[tid];
    }
    __syncthreads();
    int n = blockIdx.x * 256 + tid;
    if (n >= NN) return;
    const float4* xp = (const float4*)(x + (size_t)n * 64);
    float4 as = {0.f, 0.f, 0.f, 0.f}, ad = {0.f, 0.f, 0.f, 0.f};
#pragma unroll
    for (int i = 0; i < 16; ++i) {
        float4 xv = xp[i];
        float4 s0 = svs[i * 4 + 0], s1 = svs[i * 4 + 1], s2 = svs[i * 4 + 2], s3 = svs[i * 4 + 3];
        float4 d0 = svd[i * 4 + 0], d1 = svd[i * 4 + 1], d2 = svd[i * 4 + 2], d3 = svd[i * 4 + 3];
        as.x += xv.x * s0.x + xv.y * s1.x + xv.z * s2.x + xv.w * s3.x;
        as.y += xv.x * s0.y + xv.y * s1.y + xv.z * s2.y + xv.w * s3.y;
        as.z += xv.x * s0.z + xv.y * s1.z + xv.z * s2.z + xv.w * s3.z;
        as.w += xv.x * s0.w + xv.y * s1.w + xv.z * s2.w + xv.w * s3.w;
        ad.x += xv.x * d0.x + xv.y * d1.x + xv.z * d2.x + xv.w * d3.x;
        ad.y += xv.x * d0.y + xv.y * d1.y + xv.z * d2.y + xv.w * d3.y;
        ad.z += xv.x * d0.z + xv.y * d1.z + xv.z * d2.z + xv.w * d3.z;
        ad.w += xv.x * d0.w + xv.y * d1.w + xv.z * d2.w + xv.w * d3.w;
    }
    a4s[n] = as;
    a4d[n] = ad;
}

// ================= softmax per CSR row; stores p and inv =================
__global__ __launch_bounds__(256) void row_softmax(
    const int* __restrict__ row_ptr, const int* __restrict__ col_src,
    const float4* __restrict__ a4s, const float4* __restrict__ a4d,
    float4* __restrict__ w, float4* __restrict__ inv)
{
    int d = blockIdx.x * 256 + threadIdx.x;
    if (d >= NN) return;
    int rs = row_ptr[d], re = row_ptr[d + 1];
    float4 ad = a4d[d];
    float mx = -1e30f, my = -1e30f, mz = -1e30f, mw = -1e30f;
    for (int e = rs; e < re; ++e) {
        int s = col_src[e];
        float4 as = a4s[s];
        float4 al;
        al.x = lrelu(as.x + ad.x);
        al.y = lrelu(as.y + ad.y);
        al.z = lrelu(as.z + ad.z);
        al.w = lrelu(as.w + ad.w);
        w[e] = al;
        mx = fmaxf(mx, al.x); my = fmaxf(my, al.y);
        mz = fmaxf(mz, al.z); mw = fmaxf(mw, al.w);
    }
    float sx = 0.f, sy = 0.f, sz = 0.f, sw = 0.f;
    for (int e = rs; e < re; ++e) {
        float4 al = w[e];
        al.x = expf(al.x - mx); al.y = expf(al.y - my);
        al.z = expf(al.z - mz); al.w = expf(al.w - mw);
        w[e] = al;
        sx += al.x; sy += al.y; sz += al.z; sw += al.w;
    }
    float4 iv;
    iv.x = 0.25f / sx; iv.y = 0.25f / sy; iv.z = 0.25f / sz; iv.w = 0.25f / sw;
    inv[d] = iv;
}

// ================= gather aggregation in x-space (wave per dst) =================
__global__ __launch_bounds__(256) void gather_agg_x(
    const int* __restrict__ row_ptr, const int* __restrict__ col_src,
    const float4* __restrict__ w, const float4* __restrict__ inv,
    const float* __restrict__ x, float* __restrict__ agg)
{
    int d = (blockIdx.x * 256 + threadIdx.x) >> 6;
    int lane = threadIdx.x & 63;
    if (d >= NN) return;
    int rs = row_ptr[d], re = row_ptr[d + 1];
    float a0 = 0.f, a1 = 0.f, a2 = 0.f, a3 = 0.f;
    for (int e = rs; e < re; ++e) {
        float4 pv = w[e];                       // wave-uniform broadcast
        int s = col_src[e];                     // wave-uniform
        float xv = x[(size_t)s * 64 + lane];    // one 256B wave load
        a0 += pv.x * xv; a1 += pv.y * xv; a2 += pv.z * xv; a3 += pv.w * xv;
    }
    float4 iv = inv[d];
    float* op = agg + (size_t)d * 256;
    op[lane]       = a0 * iv.x;
    op[64 + lane]  = a1 * iv.y;
    op[128 + lane] = a2 * iv.z;
    op[192 + lane] = a3 * iv.w;
}

// ---------------- host-side GAT layer ----------------
static void gat_layer(float* x /* in/out [N,64] */, const float* W, const float* attS,
                      const float* attD, const float* b, const int* row_ptr, const int* col_src,
                      float* agg, float4* a4s, float4* a4d, float4* inv, float4* w,
                      float* vs, float* vd, float* B2, hipStream_t stream)
{
    att_vec_kernel<<<1, 256, 0, stream>>>(W, attS, attD, vs, vd);
    permW_kernel<<<64, 256, 0, stream>>>(W, B2);
    scores_x_kernel<<<(NN + 255) / 256, 256, 0, stream>>>(x, vs, vd, a4s, a4d);
    row_softmax<<<(NN + 255) / 256, 256, 0, stream>>>(row_ptr, col_src, a4s, a4d, w, inv);
    gather_agg_x<<<(NN * 64 + 255) / 256, 256, 0, stream>>>(row_ptr, col_src, w, inv, x, agg);
    // x_out = relu(agg @ B2 + b)   (0.25 folded into inv)
    gemm_kernel<<<dim3((NN + 255) / 256, 2), 256, 0, stream>>>(agg, B2, b, x, NN, 256, 64, 1);
}

extern "C" void kernel_launch(void* const* d_in, const int* in_sizes, int n_in,
                              void* d_out, int out_size, void* d_ws, size_t ws_size,
                              hipStream_t stream)
{
    const float* obs     = (const float*)d_in[0];
    const int*   ei      = (const int*)d_in[1];
    const float* enc_w1  = (const float*)d_in[2];
    const float* enc_b1  = (const float*)d_in[3];
    const float* enc_w2  = (const float*)d_in[4];
    const float* enc_b2  = (const float*)d_in[5];
    const float* gat1_w  = (const float*)d_in[6];
    const float* gat1_as = (const float*)d_in[7];
    const float* gat1_ad = (const float*)d_in[8];
    const float* gat1_b  = (const float*)d_in[9];
    const float* gat2_w  = (const float*)d_in[10];
    const float* gat2_as = (const float*)d_in[11];
    const float* gat2_ad = (const float*)d_in[12];
    const float* gat2_b  = (const float*)d_in[13];
    const float* dec_w1  = (const float*)d_in[14];
    const float* dec_b1  = (const float*)d_in[15];
    const float* dec_w2  = (const float*)d_in[16];
    const float* dec_b2  = (const float*)d_in[17];

    float* ws = (float*)d_ws;
    float* bufA    = ws;                                   // [N,64]
    float* bufB    = bufA + (size_t)NN * 64;               // [N,64]  (x)
    float* agg     = bufB + (size_t)NN * 64;               // [N,256]
    float4* a4s    = (float4*)(agg + (size_t)NN * 256);    // [N]
    float4* a4d    = a4s + NN;                             // [N]
    float4* inv    = a4d + NN;                             // [N]
    float4* w      = inv + NN;                             // [ETOT]
    int* row_ptr   = (int*)(w + (size_t)ETOT);             // [N+1] (+pad)
    int* cnt       = row_ptr + NN + 4;                     // [N]
    int* cur       = cnt + NN;                             // [N]
    int* col_src   = cur + NN;                             // [ETOT]
    int* partial   = col_src + ETOT;                       // [256]
    float* vs      = (float*)(partial + 256);              // [256]
    float* vd      = vs + 256;                             // [256]
    float* B2      = vd + 256;                             // [256*64]

    const int NB = (NN + 511) / 512;
    const int GX = (NN + 255) / 256;

    // ---- CSR build (once, reused by both GAT layers) ----
    hipMemsetAsync(cnt, 0, (size_t)NN * sizeof(int), stream);
    csr_count<<<(ETOT + 255) / 256, 256, 0, stream>>>(ei, cnt);
    scan_partial<<<NB, 256, 0, stream>>>(cnt, partial);
    scan_top<<<1, 256, 0, stream>>>(partial, NB);
    scan_final<<<NB, 256, 0, stream>>>(cnt, partial, row_ptr);
    cursor_init<<<(NN + 255) / 256, 256, 0, stream>>>(row_ptr, cur);
    csr_fill<<<(ETOT + 255) / 256, 256, 0, stream>>>(ei, cur, col_src);

    // ---- encoder ----
    gemm_kernel<<<dim3(GX, 2), 256, 0, stream>>>(obs, enc_w1, enc_b1, bufA, NN, 128, 64, 1);
    gemm_kernel<<<dim3(GX, 2), 256, 0, stream>>>(bufA, enc_w2, enc_b2, bufB, NN, 64, 64, 0);

    // ---- GAT layers (x lives in bufB) ----
    gat_layer(bufB, gat1_w, gat1_as, gat1_ad, gat1_b, row_ptr, col_src, agg, a4s, a4d, inv, w, vs, vd, B2, stream);
    gat_layer(bufB, gat2_w, gat2_as, gat2_ad, gat2_b, row_ptr, col_src, agg, a4s, a4d, inv, w, vs, vd, B2, stream);

    // ---- decoder ----
    gemm_kernel<<<dim3(GX, 2), 256, 0, stream>>>(bufB, dec_w1, dec_b1, bufA, NN, 64, 64, 1);
    gemm_kernel<<<dim3(GX, 1), 256, 0, stream>>>(bufA, dec_w2, dec_b2, (float*)d_out, NN, 64, 32, 0);
}

// Round 7
// 536.521 us; speedup vs baseline: 2.7642x; 1.1591x over previous
//
#include <hip/hip_runtime.h>
#include <math.h>

#define NN 100000
#define EE 800000
#define ETOT (EE + NN)
// HID=64, HEADS=4, OBS=128, ACT=32

// ---------------- GEMM: C[M,Nc] = A[M,K] @ B[K,Nc] (+bias, optional relu) ----------------
// 256x32 tile, 8x4 micro-tile, BK=16; conflict-engineered LDS (sA stride 260, sB stride 36).
__global__ __launch_bounds__(256) void gemm_kernel(
    const float* __restrict__ A, const float* __restrict__ B,
    const float* __restrict__ bias, float* __restrict__ C,
    int M, int K, int Nc, int doRelu)
{
    __shared__ __align__(16) float sA[16 * 260];
    __shared__ __align__(16) float sB[16 * 36];

    const int bm = blockIdx.x * 256;
    const int bn = blockIdx.y * 32;
    const int tid = threadIdx.x;
    const int ty = tid >> 3;   // 0..31
    const int tx = tid & 7;    // 0..7

    float acc[8][4] = {};

    for (int k0 = 0; k0 < K; k0 += 16) {
#pragma unroll
        for (int j = 0; j < 4; ++j) {
            int row = j * 64 + (tid >> 2);
            int cw  = tid & 3;
            int gr  = bm + row;
            float4 v = {0.f, 0.f, 0.f, 0.f};
            if (gr < M) v = *(const float4*)&A[(size_t)gr * K + k0 + cw * 4];
            sA[(cw * 4 + 0) * 260 + row] = v.x;
            sA[(cw * 4 + 1) * 260 + row] = v.y;
            sA[(cw * 4 + 2) * 260 + row] = v.z;
            sA[(cw * 4 + 3) * 260 + row] = v.w;
        }
        if (tid < 128) {
            int row = tid >> 3;
            int c4  = tid & 7;
            float4 v = {0.f, 0.f, 0.f, 0.f};
            if (bn + c4 * 4 < Nc) v = *(const float4*)&B[(size_t)(k0 + row) * Nc + bn + c4 * 4];
            *(float4*)&sB[row * 36 + c4 * 4] = v;
        }
        __syncthreads();
#pragma unroll
        for (int k = 0; k < 16; ++k) {
            float4 a0 = *(const float4*)&sA[k * 260 + ty * 4];
            float4 a1 = *(const float4*)&sA[k * 260 + 128 + ty * 4];
            float4 b0 = *(const float4*)&sB[k * 36 + tx * 4];
            float a[8] = {a0.x, a0.y, a0.z, a0.w, a1.x, a1.y, a1.z, a1.w};
            float b[4] = {b0.x, b0.y, b0.z, b0.w};
#pragma unroll
            for (int i = 0; i < 8; ++i)
#pragma unroll
                for (int j2 = 0; j2 < 4; ++j2) acc[i][j2] += a[i] * b[j2];
        }
        __syncthreads();
    }

    float bv[4] = {0.f, 0.f, 0.f, 0.f};
    int gc = bn + tx * 4;
    if (bias && gc < Nc) {
        bv[0] = bias[gc + 0]; bv[1] = bias[gc + 1];
        bv[2] = bias[gc + 2]; bv[3] = bias[gc + 3];
    }
#pragma unroll
    for (int ic = 0; ic < 2; ++ic) {
#pragma unroll
        for (int i = 0; i < 4; ++i) {
            int gr = bm + ic * 128 + ty * 4 + i;
            if (gr >= M || gc >= Nc) continue;
            float4 v;
            v.x = acc[ic * 4 + i][0] + bv[0];
            v.y = acc[ic * 4 + i][1] + bv[1];
            v.z = acc[ic * 4 + i][2] + bv[2];
            v.w = acc[ic * 4 + i][3] + bv[3];
            if (doRelu) {
                v.x = fmaxf(v.x, 0.f); v.y = fmaxf(v.y, 0.f);
                v.z = fmaxf(v.z, 0.f); v.w = fmaxf(v.w, 0.f);
            }
            *(float4*)&C[(size_t)gr * Nc + gc] = v;
        }
    }
}

__device__ __forceinline__ float lrelu(float x) { return x > 0.f ? x : 0.2f * x; }
__device__ __forceinline__ int edge_src(const int* ei, int e) { return e < EE ? ei[e] : e - EE; }
__device__ __forceinline__ int edge_dst(const int* ei, int e) { return e < EE ? ei[EE + e] : e - EE; }

// ================= CSR build =================
__global__ __launch_bounds__(256) void csr_count(const int* __restrict__ ei, int* __restrict__ cnt)
{
    int e = blockIdx.x * 256 + threadIdx.x;
    if (e >= ETOT) return;
    atomicAdd(&cnt[edge_dst(ei, e)], 1);
}

__global__ __launch_bounds__(256) void scan_partial(const int* __restrict__ cnt, int* __restrict__ partial)
{
    __shared__ int s[256];
    int b = blockIdx.x;
    int gi = b * 512 + threadIdx.x;
    int v = 0;
    if (gi < NN) v += cnt[gi];
    if (gi + 256 < NN) v += cnt[gi + 256];
    s[threadIdx.x] = v;
    __syncthreads();
    for (int off = 128; off > 0; off >>= 1) {
        if (threadIdx.x < off) s[threadIdx.x] += s[threadIdx.x + off];
        __syncthreads();
    }
    if (threadIdx.x == 0) partial[b] = s[0];
}

__global__ __launch_bounds__(256) void scan_top(int* __restrict__ partial, int nb)
{
    __shared__ int s[256];
    int tid = threadIdx.x;
    s[tid] = (tid < nb) ? partial[tid] : 0;
    __syncthreads();
    for (int off = 1; off < 256; off <<= 1) {
        int t = (tid >= off) ? s[tid - off] : 0;
        __syncthreads();
        s[tid] += t;
        __syncthreads();
    }
    if (tid < nb) partial[tid] = (tid == 0) ? 0 : s[tid - 1];
}

__global__ __launch_bounds__(256) void scan_final(
    const int* __restrict__ cnt, const int* __restrict__ partial, int* __restrict__ row_ptr)
{
    __shared__ int s[512];
    int b = blockIdx.x;
    int tid = threadIdx.x;
    int g0 = b * 512 + tid, g1 = b * 512 + tid + 256;
    s[tid]       = (g0 < NN) ? cnt[g0] : 0;
    s[tid + 256] = (g1 < NN) ? cnt[g1] : 0;
    __syncthreads();
#pragma unroll
    for (int d = 0; d < 9; ++d) {
        int stride = 1 << d, n = 256 >> d;
        if (tid < n) s[(2 * tid + 2) * stride - 1] += s[(2 * tid + 1) * stride - 1];
        __syncthreads();
    }
    if (tid == 0) s[511] = 0;
    __syncthreads();
#pragma unroll
    for (int d = 8; d >= 0; --d) {
        int stride = 1 << d, n = 256 >> d;
        if (tid < n) {
            int i1 = (2 * tid + 1) * stride - 1, i2 = (2 * tid + 2) * stride - 1;
            int t = s[i1];
            s[i1] = s[i2];
            s[i2] += t;
        }
        __syncthreads();
    }
    int off = partial[b];
    if (g0 < NN) row_ptr[g0] = s[tid] + off;
    if (g1 < NN) row_ptr[g1] = s[tid + 256] + off;
}

__global__ __launch_bounds__(256) void cursor_init(const int* __restrict__ row_ptr, int* __restrict__ cur)
{
    int i = blockIdx.x * 256 + threadIdx.x;
    if (i < NN) cur[i] = row_ptr[i];
    if (i == 0) ((int*)row_ptr)[NN] = ETOT;
}

__global__ __launch_bounds__(256) void csr_fill(
    const int* __restrict__ ei, int* __restrict__ cur, int* __restrict__ col_src)
{
    int e = blockIdx.x * 256 + threadIdx.x;
    if (e >= ETOT) return;
    int d = edge_dst(ei, e);
    int pos = atomicAdd(&cur[d], 1);
    col_src[pos] = edge_src(ei, e);
}

// ================= per-layer weight precomputes =================
__global__ __launch_bounds__(256) void att_vec_kernel(
    const float* __restrict__ W, const float* __restrict__ attS,
    const float* __restrict__ attD, float* __restrict__ vs, float* __restrict__ vd)
{
    int tid = threadIdx.x;           // tid = k*4+h
    int k = tid >> 2, h = tid & 3;
    const float* wr = W + (size_t)k * 256 + h * 64;
    const float* as = attS + h * 64;
    const float* ad = attD + h * 64;
    float ss = 0.f, sd = 0.f;
#pragma unroll
    for (int j = 0; j < 64; ++j) {
        float wv = wr[j];
        ss += wv * as[j];
        sd += wv * ad[j];
    }
    vs[tid] = ss;
    vd[tid] = sd;
}

__global__ __launch_bounds__(256) void permW_kernel(const float* __restrict__ W, float* __restrict__ B2)
{
    int i = blockIdx.x * 256 + threadIdx.x;   // i = r*64+j, r = h*64+k
    if (i >= 256 * 64) return;
    int r = i >> 6, j = i & 63;
    int h = r >> 6, k = r & 63;
    B2[i] = W[(size_t)k * 256 + h * 64 + j];
}

// ================= attention scores directly from x =================
__global__ __launch_bounds__(256) void scores_x_kernel(
    const float* __restrict__ x, const float* __restrict__ vs,
    const float* __restrict__ vd, float4* __restrict__ a4s, float4* __restrict__ a4d)
{
    __shared__ float4 svs[64], svd[64];
    int tid = threadIdx.x;
    if (tid < 64) {
        svs[tid] = ((const float4*)vs)[tid];
        svd[tid] = ((const float4*)vd)[tid];
    }
    __syncthreads();
    int n = blockIdx.x * 256 + tid;
    if (n >= NN) return;
    const float4* xp = (const float4*)(x + (size_t)n * 64);
    float4 as = {0.f, 0.f, 0.f, 0.f}, ad = {0.f, 0.f, 0.f, 0.f};
#pragma unroll
    for (int i = 0; i < 16; ++i) {
        float4 xv = xp[i];
        float4 s0 = svs[i * 4 + 0], s1 = svs[i * 4 + 1], s2 = svs[i * 4 + 2], s3 = svs[i * 4 + 3];
        float4 d0 = svd[i * 4 + 0], d1 = svd[i * 4 + 1], d2 = svd[i * 4 + 2], d3 = svd[i * 4 + 3];
        as.x += xv.x * s0.x + xv.y * s1.x + xv.z * s2.x + xv.w * s3.x;
        as.y += xv.x * s0.y + xv.y * s1.y + xv.z * s2.y + xv.w * s3.y;
        as.z += xv.x * s0.z + xv.y * s1.z + xv.z * s2.z + xv.w * s3.z;
        as.w += xv.x * s0.w + xv.y * s1.w + xv.z * s2.w + xv.w * s3.w;
        ad.x += xv.x * d0.x + xv.y * d1.x + xv.z * d2.x + xv.w * d3.x;
        ad.y += xv.x * d0.y + xv.y * d1.y + xv.z * d2.y + xv.w * d3.y;
        ad.z += xv.x * d0.z + xv.y * d1.z + xv.z * d2.z + xv.w * d3.z;
        ad.w += xv.x * d0.w + xv.y * d1.w + xv.z * d2.w + xv.w * d3.w;
    }
    a4s[n] = as;
    a4d[n] = ad;
}

// ================= softmax per CSR row (4-way unrolled gathers) =================
__global__ __launch_bounds__(256) void row_softmax(
    const int* __restrict__ row_ptr, const int* __restrict__ col_src,
    const float4* __restrict__ a4s, const float4* __restrict__ a4d,
    float4* __restrict__ w, float4* __restrict__ inv)
{
    int d = blockIdx.x * 256 + threadIdx.x;
    if (d >= NN) return;
    int rs = row_ptr[d], re = row_ptr[d + 1];
    float4 ad = a4d[d];
    float mx = -1e30f, my = -1e30f, mz = -1e30f, mw = -1e30f;

    int e = rs;
    for (; e + 4 <= re; e += 4) {
        int s0 = col_src[e + 0], s1 = col_src[e + 1];
        int s2 = col_src[e + 2], s3 = col_src[e + 3];
        float4 v0 = a4s[s0], v1 = a4s[s1], v2 = a4s[s2], v3 = a4s[s3];
        float4 al0, al1, al2, al3;
        al0.x = lrelu(v0.x + ad.x); al0.y = lrelu(v0.y + ad.y); al0.z = lrelu(v0.z + ad.z); al0.w = lrelu(v0.w + ad.w);
        al1.x = lrelu(v1.x + ad.x); al1.y = lrelu(v1.y + ad.y); al1.z = lrelu(v1.z + ad.z); al1.w = lrelu(v1.w + ad.w);
        al2.x = lrelu(v2.x + ad.x); al2.y = lrelu(v2.y + ad.y); al2.z = lrelu(v2.z + ad.z); al2.w = lrelu(v2.w + ad.w);
        al3.x = lrelu(v3.x + ad.x); al3.y = lrelu(v3.y + ad.y); al3.z = lrelu(v3.z + ad.z); al3.w = lrelu(v3.w + ad.w);
        w[e + 0] = al0; w[e + 1] = al1; w[e + 2] = al2; w[e + 3] = al3;
        mx = fmaxf(fmaxf(fmaxf(mx, al0.x), fmaxf(al1.x, al2.x)), al3.x);
        my = fmaxf(fmaxf(fmaxf(my, al0.y), fmaxf(al1.y, al2.y)), al3.y);
        mz = fmaxf(fmaxf(fmaxf(mz, al0.z), fmaxf(al1.z, al2.z)), al3.z);
        mw = fmaxf(fmaxf(fmaxf(mw, al0.w), fmaxf(al1.w, al2.w)), al3.w);
    }
    for (; e < re; ++e) {
        int s = col_src[e];
        float4 v = a4s[s];
        float4 al;
        al.x = lrelu(v.x + ad.x); al.y = lrelu(v.y + ad.y);
        al.z = lrelu(v.z + ad.z); al.w = lrelu(v.w + ad.w);
        w[e] = al;
        mx = fmaxf(mx, al.x); my = fmaxf(my, al.y);
        mz = fmaxf(mz, al.z); mw = fmaxf(mw, al.w);
    }

    float sx = 0.f, sy = 0.f, sz = 0.f, sw = 0.f;
    e = rs;
    for (; e + 2 <= re; e += 2) {
        float4 a0 = w[e], a1 = w[e + 1];
        a0.x = expf(a0.x - mx); a0.y = expf(a0.y - my); a0.z = expf(a0.z - mz); a0.w = expf(a0.w - mw);
        a1.x = expf(a1.x - mx); a1.y = expf(a1.y - my); a1.z = expf(a1.z - mz); a1.w = expf(a1.w - mw);
        w[e] = a0; w[e + 1] = a1;
        sx += a0.x + a1.x; sy += a0.y + a1.y; sz += a0.z + a1.z; sw += a0.w + a1.w;
    }
    for (; e < re; ++e) {
        float4 a0 = w[e];
        a0.x = expf(a0.x - mx); a0.y = expf(a0.y - my);
        a0.z = expf(a0.z - mz); a0.w = expf(a0.w - mw);
        w[e] = a0;
        sx += a0.x; sy += a0.y; sz += a0.z; sw += a0.w;
    }
    float4 iv;
    iv.x = 0.25f / sx; iv.y = 0.25f / sy; iv.z = 0.25f / sz; iv.w = 0.25f / sw;
    inv[d] = iv;
}

// ================= gather aggregation in x-space (wave per dst, 4-way unrolled) =================
__global__ __launch_bounds__(256) void gather_agg_x(
    const int* __restrict__ row_ptr, const int* __restrict__ col_src,
    const float4* __restrict__ w, const float4* __restrict__ inv,
    const float* __restrict__ x, float* __restrict__ agg)
{
    int d = (blockIdx.x * 256 + threadIdx.x) >> 6;
    int lane = threadIdx.x & 63;
    if (d >= NN) return;
    int rs = row_ptr[d], re = row_ptr[d + 1];
    float a0 = 0.f, a1 = 0.f, a2 = 0.f, a3 = 0.f;

    int e = rs;
    for (; e + 4 <= re; e += 4) {
        int s0 = col_src[e + 0], s1 = col_src[e + 1];
        int s2 = col_src[e + 2], s3 = col_src[e + 3];
        float4 w0 = w[e + 0], w1 = w[e + 1], w2 = w[e + 2], w3 = w[e + 3];
        float x0 = x[(size_t)s0 * 64 + lane];
        float x1 = x[(size_t)s1 * 64 + lane];
        float x2 = x[(size_t)s2 * 64 + lane];
        float x3 = x[(size_t)s3 * 64 + lane];
        a0 += w0.x * x0 + w1.x * x1 + w2.x * x2 + w3.x * x3;
        a1 += w0.y * x0 + w1.y * x1 + w2.y * x2 + w3.y * x3;
        a2 += w0.z * x0 + w1.z * x1 + w2.z * x2 + w3.z * x3;
        a3 += w0.w * x0 + w1.w * x1 + w2.w * x2 + w3.w * x3;
    }
    for (; e < re; ++e) {
        float4 pv = w[e];
        int s = col_src[e];
        float xv = x[(size_t)s * 64 + lane];
        a0 += pv.x * xv; a1 += pv.y * xv; a2 += pv.z * xv; a3 += pv.w * xv;
    }
    float4 iv = inv[d];
    float* op = agg + (size_t)d * 256;
    op[lane]       = a0 * iv.x;
    op[64 + lane]  = a1 * iv.y;
    op[128 + lane] = a2 * iv.z;
    op[192 + lane] = a3 * iv.w;
}

// ---------------- host-side GAT layer ----------------
static void gat_layer(float* x /* in/out [N,64] */, const float* W, const float* attS,
                      const float* attD, const float* b, const int* row_ptr, const int* col_src,
                      float* agg, float4* a4s, float4* a4d, float4* inv, float4* w,
                      float* vs, float* vd, float* B2, hipStream_t stream)
{
    att_vec_kernel<<<1, 256, 0, stream>>>(W, attS, attD, vs, vd);
    permW_kernel<<<64, 256, 0, stream>>>(W, B2);
    scores_x_kernel<<<(NN + 255) / 256, 256, 0, stream>>>(x, vs, vd, a4s, a4d);
    row_softmax<<<(NN + 255) / 256, 256, 0, stream>>>(row_ptr, col_src, a4s, a4d, w, inv);
    gather_agg_x<<<(NN * 64 + 255) / 256, 256, 0, stream>>>(row_ptr, col_src, w, inv, x, agg);
    // x_out = relu(agg @ B2 + b)   (0.25 folded into inv)
    gemm_kernel<<<dim3((NN + 255) / 256, 2), 256, 0, stream>>>(agg, B2, b, x, NN, 256, 64, 1);
}

extern "C" void kernel_launch(void* const* d_in, const int* in_sizes, int n_in,
                              void* d_out, int out_size, void* d_ws, size_t ws_size,
                              hipStream_t stream)
{
    const float* obs     = (const float*)d_in[0];
    const int*   ei      = (const int*)d_in[1];
    const float* enc_w1  = (const float*)d_in[2];
    const float* enc_b1  = (const float*)d_in[3];
    const float* enc_w2  = (const float*)d_in[4];
    const float* enc_b2  = (const float*)d_in[5];
    const float* gat1_w  = (const float*)d_in[6];
    const float* gat1_as = (const float*)d_in[7];
    const float* gat1_ad = (const float*)d_in[8];
    const float* gat1_b  = (const float*)d_in[9];
    const float* gat2_w  = (const float*)d_in[10];
    const float* gat2_as = (const float*)d_in[11];
    const float* gat2_ad = (const float*)d_in[12];
    const float* gat2_b  = (const float*)d_in[13];
    const float* dec_w1  = (const float*)d_in[14];
    const float* dec_b1  = (const float*)d_in[15];
    const float* dec_w2  = (const float*)d_in[16];
    const float* dec_b2  = (const float*)d_in[17];

    float* ws = (float*)d_ws;
    float* bufA    = ws;                                   // [N,64]
    float* bufB    = bufA + (size_t)NN * 64;               // [N,64]  (x)
    float* agg     = bufB + (size_t)NN * 64;               // [N,256]
    float4* a4s    = (float4*)(agg + (size_t)NN * 256);    // [N]
    float4* a4d    = a4s + NN;                             // [N]
    float4* inv    = a4d + NN;                             // [N]
    float4* w      = inv + NN;                             // [ETOT]
    int* row_ptr   = (int*)(w + (size_t)ETOT);             // [N+1] (+pad)
    int* cnt       = row_ptr + NN + 4;                     // [N]
    int* cur       = cnt + NN;                             // [N]
    int* col_src   = cur + NN;                             // [ETOT]
    int* partial   = col_src + ETOT;                       // [256]
    float* vs      = (float*)(partial + 256);              // [256]
    float* vd      = vs + 256;                             // [256]
    float* B2      = vd + 256;                             // [256*64]

    const int NB = (NN + 511) / 512;
    const int GX = (NN + 255) / 256;

    // ---- CSR build (once, reused by both GAT layers) ----
    hipMemsetAsync(cnt, 0, (size_t)NN * sizeof(int), stream);
    csr_count<<<(ETOT + 255) / 256, 256, 0, stream>>>(ei, cnt);
    scan_partial<<<NB, 256, 0, stream>>>(cnt, partial);
    scan_top<<<1, 256, 0, stream>>>(partial, NB);
    scan_final<<<NB, 256, 0, stream>>>(cnt, partial, row_ptr);
    cursor_init<<<(NN + 255) / 256, 256, 0, stream>>>(row_ptr, cur);
    csr_fill<<<(ETOT + 255) / 256, 256, 0, stream>>>(ei, cur, col_src);

    // ---- encoder ----
    gemm_kernel<<<dim3(GX, 2), 256, 0, stream>>>(obs, enc_w1, enc_b1, bufA, NN, 128, 64, 1);
    gemm_kernel<<<dim3(GX, 2), 256, 0, stream>>>(bufA, enc_w2, enc_b2, bufB, NN, 64, 64, 0);

    // ---- GAT layers (x lives in bufB) ----
    gat_layer(bufB, gat1_w, gat1_as, gat1_ad, gat1_b, row_ptr, col_src, agg, a4s, a4d, inv, w, vs, vd, B2, stream);
    gat_layer(bufB, gat2_w, gat2_as, gat2_ad, gat2_b, row_ptr, col_src, agg, a4s, a4d, inv, w, vs, vd, B2, stream);

    // ---- decoder ----
    gemm_kernel<<<dim3(GX, 2), 256, 0, stream>>>(bufB, dec_w1, dec_b1, bufA, NN, 64, 64, 1);
    gemm_kernel<<<dim3(GX, 1), 256, 0, stream>>>(bufA, dec_w2, dec_b2, (float*)d_out, NN, 64, 32, 0);
}